// Round 3
// baseline (5181.145 us; speedup 1.0000x reference)
//
#include <hip/hip_runtime.h>

typedef unsigned short u16;
typedef unsigned int u32;
typedef unsigned long long u64;
typedef __attribute__((ext_vector_type(8))) short short8;
typedef __attribute__((ext_vector_type(4))) float f32x4;
typedef __attribute__((ext_vector_type(2))) _Float16 f16x2;

#define B_ 64
#define T_ 1024
#define D2_ 512
#define HD_ 256
#define G4_ 1024
#define PD_ 100
#define KX_ 640
#define KO_ 768
#define LBL_ 96
#define LPAD_ 128

__device__ __forceinline__ float bf2f(u16 u) {
  u32 v = ((u32)u) << 16;
  return __builtin_bit_cast(float, v);
}
__device__ __forceinline__ u16 f2bf(float f) {
  u32 u = __builtin_bit_cast(u32, f);
  u32 r = (u + 0x7fffu + ((u >> 16) & 1u)) >> 16;
  return (u16)r;
}
// fast sigmoid/tanh via v_exp_f32 (base-2) + v_rcp; saturate correctly at +-inf
__device__ __forceinline__ float sgm(float x) {
  return __builtin_amdgcn_rcpf(1.f + __builtin_amdgcn_exp2f(-1.442695040888963f * x));
}
__device__ __forceinline__ float thh(float x) {
  return fmaf(-2.f,
              __builtin_amdgcn_rcpf(1.f + __builtin_amdgcn_exp2f(2.885390081777927f * x)),
              1.f);
}

// ---------------- K0: weight prep (f32 -> bf16, padding, bias fuse) ----------
__global__ __launch_bounds__(256) void k_prep(
    const float* combW, const float* Wih, const float* bih, const float* Whh,
    const float* bhh, const float* linW, u16* wc, u16* wih, u16* whh, u16* wlin,
    float* biasg) {
  int idx = blockIdx.x * 256 + threadIdx.x;
  if (idx < 256 * KX_) {  // comb_W [256][612] -> [256][640] zero-padded
    int r = idx / KX_, c = idx % KX_;
    wc[idx] = f2bf(c < 612 ? combW[r * 612 + c] : 0.f);
    return;
  }
  idx -= 256 * KX_;
  if (idx < G4_ * HD_) { wih[idx] = f2bf(Wih[idx]); return; }
  idx -= G4_ * HD_;
  if (idx < G4_ * HD_) { whh[idx] = f2bf(Whh[idx]); return; }
  idx -= G4_ * HD_;
  if (idx < LPAD_ * KO_) {  // lin_W [96][768] -> [128][768] zero rows 96..127
    int r = idx / KO_;
    wlin[idx] = f2bf(r < LBL_ ? linW[idx] : 0.f);
    return;
  }
  idx -= LPAD_ * KO_;
  if (idx < G4_) biasg[idx] = bih[idx] + bhh[idx];
}

// ---------------- K1: prefix sums P[b][t][d] = sum_{u<t} enc[b][u][d] --------
__global__ __launch_bounds__(256) void k_prefix(const float* enc, float* P) {
  int id = blockIdx.x * 256 + threadIdx.x;
  int b = id >> 9, d = id & 511;
  const float* e = enc + (size_t)b * T_ * D2_ + d;
  float* p = P + (size_t)b * T_ * D2_ + d;
  float acc = 0.f;
  for (int t = 0; t < T_; ++t) {
    p[(size_t)t * D2_] = acc;
    acc += e[(size_t)t * D2_];
  }
}

// ---------------- K2: X rows [pe(100) | avg(512) | pad(28)] bf16 -------------
__global__ __launch_bounds__(256) void k_xbuild(const float* P, const float* ptab,
                                                const int* pid, const int* sidx,
                                                u16* X) {
  int m = blockIdx.x;  // m = t*64 + b
  int t = m >> 6, b = m & 63;
  int pp = 0, ps = 0;
  if (t > 0) {
    pp = pid[(t - 1) * B_ + b];
    ps = sidx[(t - 1) * B_ + b];
  }
  bool valid = (ps >= 0) && (t > 0);
  int start = min(ps, t - 1);
  if (start < 0) start = 0;
  if (start > T_ - 1) start = T_ - 1;
  float invlen = 1.f / (float)max(t - start, 1);
  const float* Pt = P + ((size_t)b * T_ + t) * D2_;
  const float* Psrc = P + ((size_t)b * T_ + start) * D2_;
  u16* xr = X + (size_t)m * KX_;
  for (int k = threadIdx.x; k < KX_; k += 256) {
    float v;
    if (k < PD_) v = ptab[pp * PD_ + k];
    else if (k < 612) {
      int d = k - PD_;
      v = valid ? (Pt[d] - Psrc[d]) * invlen : 0.f;
    } else v = 0.f;
    xr[k] = f2bf(v);
  }
}

// ---------------- generic 64x64-tile bf16 MFMA GEMM: out = A @ Bw^T ----------
template <int MODE>
__global__ __launch_bounds__(256) void k_gemm(const u16* A, const float* A2f,
                                              const u16* Bw, int K, int lda,
                                              const float* bias, u16* outb,
                                              float* outf) {
  __shared__ u16 As[64][40];
  __shared__ u16 Bs[64][40];
  const int m0 = blockIdx.x * 64, n0 = blockIdx.y * 64;
  const int tid = threadIdx.x;
  const int srow = tid >> 2, sc8 = (tid & 3) * 8;
  const int w = tid >> 6, l = tid & 63;
  const int l15 = l & 15, lh = l >> 4;
  f32x4 acc[4] = {};
  for (int k0 = 0; k0 < K; k0 += 32) {
    int k = k0 + sc8;
    uint4 av;
    if constexpr (MODE == 2) {
      if (k < 256) {
        av = *(const uint4*)(A + (size_t)(m0 + srow) * 256 + k);
      } else {
        const float* src = A2f + (size_t)(m0 + srow) * 512 + (k - 256);
        float4 f0 = *(const float4*)(src);
        float4 f1 = *(const float4*)(src + 4);
        av.x = (u32)f2bf(f0.x) | ((u32)f2bf(f0.y) << 16);
        av.y = (u32)f2bf(f0.z) | ((u32)f2bf(f0.w) << 16);
        av.z = (u32)f2bf(f1.x) | ((u32)f2bf(f1.y) << 16);
        av.w = (u32)f2bf(f1.z) | ((u32)f2bf(f1.w) << 16);
      }
    } else {
      av = *(const uint4*)(A + (size_t)(m0 + srow) * lda + k);
    }
    *(uint4*)&As[srow][sc8] = av;
    uint4 bv = *(const uint4*)(Bw + (size_t)(n0 + srow) * K + k);
    *(uint4*)&Bs[srow][sc8] = bv;
    __syncthreads();
    short8 a8 = *(const short8*)&As[16 * w + l15][lh * 8];
#pragma unroll
    for (int nt = 0; nt < 4; ++nt) {
      short8 b8 = *(const short8*)&Bs[nt * 16 + l15][lh * 8];
      acc[nt] = __builtin_amdgcn_mfma_f32_16x16x32_bf16(a8, b8, acc[nt], 0, 0, 0);
    }
    __syncthreads();
  }
#pragma unroll
  for (int nt = 0; nt < 4; ++nt) {
#pragma unroll
    for (int r = 0; r < 4; ++r) {
      int gm = m0 + 16 * w + lh * 4 + r;
      int gn = n0 + nt * 16 + l15;
      float v = acc[nt][r];
      if constexpr (MODE == 0) {
        v = tanhf(v + bias[gn]);
        if (gm < 64) v = 0.f;
        outb[(size_t)gm * 256 + gn] = f2bf(v);
      } else if constexpr (MODE == 1) {
        v += bias[gn];
        outb[(size_t)gm * 1024 + gn] = f2bf(v);
      } else {
        if (gn < LBL_) {
          if ((gm & (T_ - 1)) == 0 && gn == 1) v = -1e10f;
          outf[(size_t)gm * LBL_ + gn] = v;
        }
      }
    }
  }
}

// ---------------- K5: sequential LSTM via MFMA, one block per batch ----------
// 16 waves; wave w owns cells [w*16, w*16+16). Its 4 N-tiles are the 4 gate
// types of those cells, so the LSTM cell update never leaves registers.
// A-operand = h replicated across all 16 M rows (uniform-per-quad LDS read);
// C-in = G broadcast across rows, so every lane's acc holds the true gates.
__global__ __launch_bounds__(1024, 4) void k_seq(const u16* G, const u16* whh,
                                                 u16* Hout) {
  __shared__ __align__(16) u16 hbuf[2][256];  // h as f16, double-buffered
  const int b = blockIdx.x;
  const int tid = threadIdx.x;
  const int w = tid >> 6, l = tid & 63;
  const int c16 = l & 15, quad = l >> 4;
  const int cell = w * 16 + c16;
  // B-fragments: Bf[gate_type][k_tile], weight row = nt*256 + cell
  short8 Bf[4][8];
#pragma unroll
  for (int nt = 0; nt < 4; ++nt)
#pragma unroll
    for (int kt = 0; kt < 8; ++kt)
      Bf[nt][kt] = *(const short8*)(whh + (size_t)(nt * 256 + cell) * 256 +
                                    kt * 32 + quad * 8);
  if (tid < 256) hbuf[0][tid] = 0;
  const u16* gbase = G + (size_t)b * 1024 + cell;  // + t*65536 + nt*256
  u16 gv[4];
#pragma unroll
  for (int nt = 0; nt < 4; ++nt) gv[nt] = gbase[nt * 256];
  float c = 0.f;
  int cur = 0;
  __syncthreads();
  for (int t = 0; t < T_; ++t) {
    // prefetch next step's gate biases
    int tn = (t + 1 < T_) ? t + 1 : t;
    u16 ngv[4];
#pragma unroll
    for (int nt = 0; nt < 4; ++nt)
      ngv[nt] = gbase[(size_t)tn * 65536 + nt * 256];
    f32x4 acc[4];
#pragma unroll
    for (int nt = 0; nt < 4; ++nt) {
      float g = bf2f(gv[nt]);
      acc[nt] = (f32x4){g, g, g, g};
    }
#pragma unroll
    for (int kt = 0; kt < 8; ++kt) {
      short8 a = *(const short8*)&hbuf[cur][kt * 32 + quad * 8];
#pragma unroll
      for (int nt = 0; nt < 4; ++nt)
        acc[nt] = __builtin_amdgcn_mfma_f32_16x16x32_bf16(a, Bf[nt][kt],
                                                          acc[nt], 0, 0, 0);
    }
    float gi = acc[0][0], gf = acc[1][0], gg = acc[2][0], go = acc[3][0];
    c = sgm(gf) * c + sgm(gi) * thh(gg);
    float h = sgm(go) * thh(c);
    if (l < 16) {
      u32 pk = __builtin_bit_cast(u32, __builtin_amdgcn_cvt_pkrtz(h, h));
      hbuf[cur ^ 1][cell] = (u16)pk;
      Hout[((size_t)b * 1024 + t) * 256 + cell] = f2bf(h);
    }
#pragma unroll
    for (int nt = 0; nt < 4; ++nt) gv[nt] = ngv[nt];
    cur ^= 1;
    __syncthreads();
  }
}

// ---------------- K7: in-place row log-softmax on d_out ----------------------
__global__ __launch_bounds__(256) void k_lsm(float* out) {
  int row = blockIdx.x * 4 + (threadIdx.x >> 6);
  int l = threadIdx.x & 63;
  float* r = out + (size_t)row * LBL_;
  float v0 = r[l];
  float v1 = (l < 32) ? r[64 + l] : -__builtin_inff();
  float mx = fmaxf(v0, v1);
#pragma unroll
  for (int s = 32; s; s >>= 1) mx = fmaxf(mx, __shfl_xor(mx, s));
  float s0 = expf(v0 - mx) + ((l < 32) ? expf(v1 - mx) : 0.f);
#pragma unroll
  for (int s = 32; s; s >>= 1) s0 += __shfl_xor(s0, s);
  float lg = logf(s0) + mx;
  r[l] = v0 - lg;
  if (l < 32) r[64 + l] = v1 - lg;
}

extern "C" void kernel_launch(void* const* d_in, const int* in_sizes, int n_in,
                              void* d_out, int out_size, void* d_ws, size_t ws_size,
                              hipStream_t stream) {
  const float* enc = (const float*)d_in[0];
  const float* ptab = (const float*)d_in[1];
  const float* Wih = (const float*)d_in[2];
  const float* bih = (const float*)d_in[3];
  const float* Whh = (const float*)d_in[4];
  const float* bhh = (const float*)d_in[5];
  const float* combW = (const float*)d_in[6];
  const float* combb = (const float*)d_in[7];
  const float* linW = (const float*)d_in[8];
  const int* pid = (const int*)d_in[9];
  const int* sidx = (const int*)d_in[10];

  char* ws = (char*)d_ws;
  size_t off = 0;
  auto alloc = [&](size_t bytes) {
    void* p = ws + off;
    off += (bytes + 255) & ~(size_t)255;
    return p;
  };
  float* P = (float*)alloc((size_t)B_ * T_ * D2_ * 4);  // -> aliased by G
  u16* Xb = (u16*)alloc((size_t)T_ * B_ * KX_ * 2);     // -> aliased by H
  u16* Z = (u16*)alloc((size_t)T_ * B_ * HD_ * 2);
  u16* wc = (u16*)alloc(256 * KX_ * 2);
  u16* wih = (u16*)alloc(G4_ * HD_ * 2);
  u16* whh = (u16*)alloc(G4_ * HD_ * 2);
  u16* wlin = (u16*)alloc(LPAD_ * KO_ * 2);
  float* biasg = (float*)alloc(G4_ * 4);
  u16* G = (u16*)P;
  u16* Hs = (u16*)Xb;
  float* out = (float*)d_out;

  k_prep<<<3076, 256, 0, stream>>>(combW, Wih, bih, Whh, bhh, linW, wc, wih, whh,
                                   wlin, biasg);
  k_prefix<<<128, 256, 0, stream>>>(enc, P);
  k_xbuild<<<T_ * B_, 256, 0, stream>>>(P, ptab, pid, sidx, Xb);
  dim3 g3(1024, 4);
  k_gemm<0><<<g3, 256, 0, stream>>>(Xb, nullptr, wc, KX_, KX_, combb, Z, nullptr);
  dim3 g4(1024, 16);
  k_gemm<1><<<g4, 256, 0, stream>>>(Z, nullptr, wih, HD_, HD_, biasg, G, nullptr);
  k_seq<<<B_, 1024, 0, stream>>>(G, whh, Hs);
  dim3 g6(1024, 2);
  k_gemm<2><<<g6, 256, 0, stream>>>(Hs, enc, wlin, KO_, 0, nullptr, nullptr, out);
  k_lsm<<<(T_ * B_) / 4, 256, 0, stream>>>(out);
}

// Round 4
// 1979.848 us; speedup vs baseline: 2.6169x; 2.6169x over previous
//
#include <hip/hip_runtime.h>

typedef unsigned short u16;
typedef unsigned int u32;
typedef unsigned long long u64;
typedef __attribute__((ext_vector_type(8))) short short8;
typedef __attribute__((ext_vector_type(4))) float f32x4;

#define B_ 64
#define T_ 1024
#define D2_ 512
#define HD_ 256
#define G4_ 1024
#define PD_ 100
#define KX_ 640
#define KO_ 768
#define LBL_ 96
#define LPAD_ 128

__device__ __forceinline__ float bf2f(u16 u) {
  u32 v = ((u32)u) << 16;
  return __builtin_bit_cast(float, v);
}
__device__ __forceinline__ u16 f2bf(float f) {
  u32 u = __builtin_bit_cast(u32, f);
  u32 r = (u + 0x7fffu + ((u >> 16) & 1u)) >> 16;
  return (u16)r;
}
__device__ __forceinline__ float sgm(float x) {
  return __builtin_amdgcn_rcpf(1.f + __builtin_amdgcn_exp2f(-1.442695040888963f * x));
}
__device__ __forceinline__ float thh(float x) {
  return fmaf(-2.f,
              __builtin_amdgcn_rcpf(1.f + __builtin_amdgcn_exp2f(2.885390081777927f * x)),
              1.f);
}
// k-permutation for the fp8 recurrence: original k -> byte position. Applied
// identically to h (A) and W_hh rows (B), so the MFMA dot is unaffected; it
// makes a thread's 8 A-slices contiguous in pairs (4 x b128 reads per step).
__device__ __forceinline__ int kpos(int c) {
  return ((c >> 6) << 6) + (((c >> 5) & 1) << 3) + (((c >> 3) & 3) << 4) + (c & 7);
}

// ---------------- K0: weight prep ----------------
// wc: comb_W bf16 [256][640] padded; wih: W_ih bf16; w8: W_hh fp8 e4m3
// [1024][256] k-permuted; wlin: lin_W bf16 [128][768]; biasg = b_ih + b_hh
__global__ __launch_bounds__(256) void k_prep(
    const float* combW, const float* Wih, const float* bih, const float* Whh,
    const float* bhh, const float* linW, u16* wc, u16* wih, u16* w8, u16* wlin,
    float* biasg) {
  int idx = blockIdx.x * 256 + threadIdx.x;
  if (idx < 256 * KX_) {
    int r = idx / KX_, c = idx % KX_;
    wc[idx] = f2bf(c < 612 ? combW[r * 612 + c] : 0.f);
    return;
  }
  idx -= 256 * KX_;
  if (idx < G4_ * HD_) { wih[idx] = f2bf(Wih[idx]); return; }
  idx -= G4_ * HD_;
  if (idx < G4_ * HD_ / 2) {  // fp8 pair (k even): pos(c+1) == pos(c)+1
    int n = idx >> 7, c = (idx & 127) * 2;
    int p = kpos(c);
    int pk = __builtin_amdgcn_cvt_pk_fp8_f32(Whh[n * 256 + c], Whh[n * 256 + c + 1],
                                             0, false);
    w8[((size_t)n * 256 + p) >> 1] = (u16)(pk & 0xffff);
    return;
  }
  idx -= G4_ * HD_ / 2;
  if (idx < LPAD_ * KO_) {
    int r = idx / KO_;
    wlin[idx] = f2bf(r < LBL_ ? linW[idx] : 0.f);
    return;
  }
  idx -= LPAD_ * KO_;
  if (idx < G4_) biasg[idx] = bih[idx] + bhh[idx];
}

// ---------------- K1: prefix sums ----------------
__global__ __launch_bounds__(256) void k_prefix(const float* enc, float* P) {
  int id = blockIdx.x * 256 + threadIdx.x;
  int b = id >> 9, d = id & 511;
  const float* e = enc + (size_t)b * T_ * D2_ + d;
  float* p = P + (size_t)b * T_ * D2_ + d;
  float acc = 0.f;
  for (int t = 0; t < T_; ++t) {
    p[(size_t)t * D2_] = acc;
    acc += e[(size_t)t * D2_];
  }
}

// ---------------- K2: X rows [pe(100) | avg(512) | pad(28)] bf16 -------------
__global__ __launch_bounds__(256) void k_xbuild(const float* P, const float* ptab,
                                                const int* pid, const int* sidx,
                                                u16* X) {
  int m = blockIdx.x;  // m = t*64 + b
  int t = m >> 6, b = m & 63;
  int pp = 0, ps = 0;
  if (t > 0) {
    pp = pid[(t - 1) * B_ + b];
    ps = sidx[(t - 1) * B_ + b];
  }
  bool valid = (ps >= 0) && (t > 0);
  int start = min(ps, t - 1);
  if (start < 0) start = 0;
  if (start > T_ - 1) start = T_ - 1;
  float invlen = 1.f / (float)max(t - start, 1);
  const float* Pt = P + ((size_t)b * T_ + t) * D2_;
  const float* Psrc = P + ((size_t)b * T_ + start) * D2_;
  u16* xr = X + (size_t)m * KX_;
  for (int k = threadIdx.x; k < KX_; k += 256) {
    float v;
    if (k < PD_) v = ptab[pp * PD_ + k];
    else if (k < 612) {
      int d = k - PD_;
      v = valid ? (Pt[d] - Psrc[d]) * invlen : 0.f;
    } else v = 0.f;
    xr[k] = f2bf(v);
  }
}

// ---------------- generic 64x64-tile bf16 MFMA GEMM: out = A @ Bw^T ----------
// MODE 0: Z = tanh(X@Wc^T + comb_b), zero rows m<64, bf16 out, N=256
// MODE 1: G = Z@Wih^T + biasg -> PERMUTED gate layout for k_seq, N=1024
//         blockIdx.y = q: rows n = g*256 + q*16 + i (g<4, i<16)
// MODE 2: Out = [H|enc]@lin^T, f32 out to d_out (cols<96), -1e10 fixup
template <int MODE>
__global__ __launch_bounds__(256) void k_gemm(const u16* A, const float* A2f,
                                              const u16* Bw, int K, int lda,
                                              const float* bias, u16* outb,
                                              float* outf) {
  __shared__ u16 As[64][40];
  __shared__ u16 Bs[64][40];
  const int m0 = blockIdx.x * 64, n0 = blockIdx.y * 64;
  const int tid = threadIdx.x;
  const int srow = tid >> 2, sc8 = (tid & 3) * 8;
  const int w = tid >> 6, l = tid & 63;
  const int l15 = l & 15, lh = l >> 4;
  f32x4 acc[4] = {};
  for (int k0 = 0; k0 < K; k0 += 32) {
    int k = k0 + sc8;
    uint4 av;
    if constexpr (MODE == 2) {
      if (k < 256) {
        av = *(const uint4*)(A + (size_t)(m0 + srow) * 256 + k);
      } else {
        const float* src = A2f + (size_t)(m0 + srow) * 512 + (k - 256);
        float4 f0 = *(const float4*)(src);
        float4 f1 = *(const float4*)(src + 4);
        av.x = (u32)f2bf(f0.x) | ((u32)f2bf(f0.y) << 16);
        av.y = (u32)f2bf(f0.z) | ((u32)f2bf(f0.w) << 16);
        av.z = (u32)f2bf(f1.x) | ((u32)f2bf(f1.y) << 16);
        av.w = (u32)f2bf(f1.z) | ((u32)f2bf(f1.w) << 16);
      }
    } else {
      av = *(const uint4*)(A + (size_t)(m0 + srow) * lda + k);
    }
    *(uint4*)&As[srow][sc8] = av;
    uint4 bv;
    if constexpr (MODE == 1) {
      int n = ((srow >> 4) << 8) + (int)blockIdx.y * 16 + (srow & 15);
      bv = *(const uint4*)(Bw + (size_t)n * K + k);
    } else {
      bv = *(const uint4*)(Bw + (size_t)(n0 + srow) * K + k);
    }
    *(uint4*)&Bs[srow][sc8] = bv;
    __syncthreads();
    short8 a8 = *(const short8*)&As[16 * w + l15][lh * 8];
#pragma unroll
    for (int nt = 0; nt < 4; ++nt) {
      short8 b8 = *(const short8*)&Bs[nt * 16 + l15][lh * 8];
      acc[nt] = __builtin_amdgcn_mfma_f32_16x16x32_bf16(a8, b8, acc[nt], 0, 0, 0);
    }
    __syncthreads();
  }
#pragma unroll
  for (int nt = 0; nt < 4; ++nt) {
#pragma unroll
    for (int r = 0; r < 4; ++r) {
      int gm = m0 + 16 * w + lh * 4 + r;
      float v = acc[nt][r];
      if constexpr (MODE == 0) {
        int gn = n0 + nt * 16 + l15;
        v = tanhf(v + bias[gn]);
        if (gm < 64) v = 0.f;
        outb[(size_t)gm * 256 + gn] = f2bf(v);
      } else if constexpr (MODE == 1) {
        int q = blockIdx.y;
        int na = nt * 256 + q * 16 + l15;
        v += bias[na];
        int j = (((q >> 1) * 16 + l15) << 3) + ((q & 1) << 2) + nt;
        outb[(size_t)gm * 1024 + j] = f2bf(v);
      } else {
        int gn = n0 + nt * 16 + l15;
        if (gn < LBL_) {
          if ((gm & (T_ - 1)) == 0 && gn == 1) v = -1e10f;
          outf[(size_t)gm * LBL_ + gn] = v;
        }
      }
    }
  }
}

// ---------------- K5: sequential LSTM via fp8 MFMA, one block per batch ------
// 8 waves (2/SIMD -> 256-reg cap). Wave w owns cells [w*32, w*32+32):
// 2 cell-tiles x 4 gates = 64 fp8 B-frags = 128 VGPRs, register-resident.
// h lives in LDS as 256 fp8 bytes (k-permuted); A = h broadcast across M.
// C-init = G gate biases (prefetched, coalesced b128 per lane).
__global__ __launch_bounds__(512, 2) void k_seq(const u16* G, const u16* w8,
                                                u16* Hout) {
  __shared__ __align__(16) unsigned char hq[2][256];
  const int b = blockIdx.x;
  const int tid = threadIdx.x;
  const int w = tid >> 6, l = tid & 63;
  const int c16 = l & 15, quad = l >> 4;
  const int cA = w * 32 + c16, cB = cA + 16;
  const unsigned char* w8b = (const unsigned char*)w8;
  u64 Bf[2][4][8];
#pragma unroll
  for (int ct = 0; ct < 2; ++ct)
#pragma unroll
    for (int g = 0; g < 4; ++g) {
      int n = g * 256 + w * 32 + ct * 16 + c16;
#pragma unroll
      for (int kt = 0; kt < 8; ++kt) {
        int ofs = ((kt >> 1) << 6) + ((kt & 1) << 3) + (quad << 4);
        Bf[ct][g][kt] = *(const u64*)(w8b + (size_t)n * 256 + ofs);
      }
    }
  if (tid < 256) hq[0][tid] = 0;
  const u16* gbase = G + (size_t)b * 1024 + (size_t)(w * 16 + c16) * 8;
  uint4 gv = *(const uint4*)gbase;
  const int posA = kpos(cA), posB = kpos(cB);
  float cc0 = 0.f, cc1 = 0.f;
  int cur = 0;
  __syncthreads();
  for (int t = 0; t < T_; ++t) {
    int tn = (t + 1 < T_) ? t + 1 : t;
    uint4 ngv = *(const uint4*)(gbase + (size_t)tn * 65536);
    f32x4 acc[2][4];
    {
      float g0 = bf2f((u16)(gv.x & 0xffff)), g1 = bf2f((u16)(gv.x >> 16));
      float g2 = bf2f((u16)(gv.y & 0xffff)), g3 = bf2f((u16)(gv.y >> 16));
      float g4 = bf2f((u16)(gv.z & 0xffff)), g5 = bf2f((u16)(gv.z >> 16));
      float g6 = bf2f((u16)(gv.w & 0xffff)), g7 = bf2f((u16)(gv.w >> 16));
      acc[0][0] = (f32x4){g0, g0, g0, g0};
      acc[0][1] = (f32x4){g1, g1, g1, g1};
      acc[0][2] = (f32x4){g2, g2, g2, g2};
      acc[0][3] = (f32x4){g3, g3, g3, g3};
      acc[1][0] = (f32x4){g4, g4, g4, g4};
      acc[1][1] = (f32x4){g5, g5, g5, g5};
      acc[1][2] = (f32x4){g6, g6, g6, g6};
      acc[1][3] = (f32x4){g7, g7, g7, g7};
    }
#pragma unroll
    for (int kt2 = 0; kt2 < 4; ++kt2) {
      uint4 av = *(const uint4*)&hq[cur][kt2 * 64 + quad * 16];
      u64 alo = ((u64)av.y << 32) | av.x;
      u64 ahi = ((u64)av.w << 32) | av.z;
#pragma unroll
      for (int ct = 0; ct < 2; ++ct)
#pragma unroll
        for (int g = 0; g < 4; ++g) {
          acc[ct][g] = __builtin_amdgcn_mfma_f32_16x16x32_fp8_fp8(
              (long)alo, (long)Bf[ct][g][2 * kt2], acc[ct][g], 0, 0, 0);
          acc[ct][g] = __builtin_amdgcn_mfma_f32_16x16x32_fp8_fp8(
              (long)ahi, (long)Bf[ct][g][2 * kt2 + 1], acc[ct][g], 0, 0, 0);
        }
    }
    float gi0 = acc[0][0][0], gf0 = acc[0][1][0], gg0 = acc[0][2][0], go0 = acc[0][3][0];
    float gi1 = acc[1][0][0], gf1 = acc[1][1][0], gg1 = acc[1][2][0], go1 = acc[1][3][0];
    cc0 = sgm(gf0) * cc0 + sgm(gi0) * thh(gg0);
    cc1 = sgm(gf1) * cc1 + sgm(gi1) * thh(gg1);
    float h0 = sgm(go0) * thh(cc0);
    float h1 = sgm(go1) * thh(cc1);
    if (l < 16) {
      int p8 = __builtin_amdgcn_cvt_pk_fp8_f32(h0, h1, 0, false);
      hq[cur ^ 1][posA] = (unsigned char)(p8 & 0xff);
      hq[cur ^ 1][posB] = (unsigned char)((p8 >> 8) & 0xff);
      u16* ho = Hout + ((size_t)b * 1024 + t) * 256 + cA;
      ho[0] = f2bf(h0);
      ho[16] = f2bf(h1);
    }
    gv = ngv;
    cur ^= 1;
    __syncthreads();
  }
}

// ---------------- K7: in-place row log-softmax on d_out ----------------------
__global__ __launch_bounds__(256) void k_lsm(float* out) {
  int row = blockIdx.x * 4 + (threadIdx.x >> 6);
  int l = threadIdx.x & 63;
  float* r = out + (size_t)row * LBL_;
  float v0 = r[l];
  float v1 = (l < 32) ? r[64 + l] : -__builtin_inff();
  float mx = fmaxf(v0, v1);
#pragma unroll
  for (int s = 32; s; s >>= 1) mx = fmaxf(mx, __shfl_xor(mx, s));
  float s0 = expf(v0 - mx) + ((l < 32) ? expf(v1 - mx) : 0.f);
#pragma unroll
  for (int s = 32; s; s >>= 1) s0 += __shfl_xor(s0, s);
  float lg = logf(s0) + mx;
  r[l] = v0 - lg;
  if (l < 32) r[64 + l] = v1 - lg;
}

extern "C" void kernel_launch(void* const* d_in, const int* in_sizes, int n_in,
                              void* d_out, int out_size, void* d_ws, size_t ws_size,
                              hipStream_t stream) {
  const float* enc = (const float*)d_in[0];
  const float* ptab = (const float*)d_in[1];
  const float* Wih = (const float*)d_in[2];
  const float* bih = (const float*)d_in[3];
  const float* Whh = (const float*)d_in[4];
  const float* bhh = (const float*)d_in[5];
  const float* combW = (const float*)d_in[6];
  const float* combb = (const float*)d_in[7];
  const float* linW = (const float*)d_in[8];
  const int* pid = (const int*)d_in[9];
  const int* sidx = (const int*)d_in[10];

  char* ws = (char*)d_ws;
  size_t off = 0;
  auto alloc = [&](size_t bytes) {
    void* p = ws + off;
    off += (bytes + 255) & ~(size_t)255;
    return p;
  };
  float* P = (float*)alloc((size_t)B_ * T_ * D2_ * 4);  // -> aliased by G
  u16* Xb = (u16*)alloc((size_t)T_ * B_ * KX_ * 2);     // -> aliased by H
  u16* Z = (u16*)alloc((size_t)T_ * B_ * HD_ * 2);
  u16* wc = (u16*)alloc(256 * KX_ * 2);
  u16* wih = (u16*)alloc(G4_ * HD_ * 2);
  u16* w8 = (u16*)alloc(G4_ * HD_);  // fp8 bytes
  u16* wlin = (u16*)alloc(LPAD_ * KO_ * 2);
  float* biasg = (float*)alloc(G4_ * 4);
  u16* G = (u16*)P;
  u16* Hs = (u16*)Xb;
  float* out = (float*)d_out;

  k_prep<<<2564, 256, 0, stream>>>(combW, Wih, bih, Whh, bhh, linW, wc, wih, w8,
                                   wlin, biasg);
  k_prefix<<<128, 256, 0, stream>>>(enc, P);
  k_xbuild<<<T_ * B_, 256, 0, stream>>>(P, ptab, pid, sidx, Xb);
  dim3 g3(1024, 4);
  k_gemm<0><<<g3, 256, 0, stream>>>(Xb, nullptr, wc, KX_, KX_, combb, Z, nullptr);
  dim3 g4(1024, 16);
  k_gemm<1><<<g4, 256, 0, stream>>>(Z, nullptr, wih, HD_, HD_, biasg, G, nullptr);
  k_seq<<<B_, 512, 0, stream>>>(G, w8, Hs);
  dim3 g6(1024, 2);
  k_gemm<2><<<g6, 256, 0, stream>>>(Hs, enc, wlin, KO_, 0, nullptr, nullptr, out);
  k_lsm<<<(T_ * B_) / 4, 256, 0, stream>>>(out);
}

// Round 5
// 1626.317 us; speedup vs baseline: 3.1858x; 1.2174x over previous
//
#include <hip/hip_runtime.h>

typedef unsigned short u16;
typedef unsigned int u32;
typedef unsigned long long u64;
typedef __attribute__((ext_vector_type(8))) short short8;
typedef __attribute__((ext_vector_type(4))) float f32x4;
typedef __attribute__((ext_vector_type(8))) int i32x8;

#define B_ 64
#define T_ 1024
#define D2_ 512
#define HD_ 256
#define G4_ 1024
#define PD_ 100
#define KX_ 640
#define KO_ 768
#define LBL_ 96
#define LPAD_ 128
#define SCONE 0x7f7f7f7f  // e8m0 scale bytes: 2^0 = 1.0 in all 4 positions

__device__ __forceinline__ float bf2f(u16 u) {
  u32 v = ((u32)u) << 16;
  return __builtin_bit_cast(float, v);
}
__device__ __forceinline__ u16 f2bf(float f) {
  u32 u = __builtin_bit_cast(u32, f);
  u32 r = (u + 0x7fffu + ((u >> 16) & 1u)) >> 16;
  return (u16)r;
}
__device__ __forceinline__ float sgm(float x) {
  return __builtin_amdgcn_rcpf(1.f + __builtin_amdgcn_exp2f(-1.442695040888963f * x));
}
__device__ __forceinline__ float thh(float x) {
  return fmaf(-2.f,
              __builtin_amdgcn_rcpf(1.f + __builtin_amdgcn_exp2f(2.885390081777927f * x)),
              1.f);
}

// ---------------- K0: weight prep ----------------
// wc: comb_W bf16 [256][640] padded; wih: W_ih bf16; w8: W_hh fp8 e4m3
// [1024][256] k-linear; wlin: lin_W bf16 [128][768]; biasg = b_ih + b_hh
__global__ __launch_bounds__(256) void k_prep(
    const float* combW, const float* Wih, const float* bih, const float* Whh,
    const float* bhh, const float* linW, u16* wc, u16* wih, u16* w8, u16* wlin,
    float* biasg) {
  int idx = blockIdx.x * 256 + threadIdx.x;
  if (idx < 256 * KX_) {
    int r = idx / KX_, c = idx % KX_;
    wc[idx] = f2bf(c < 612 ? combW[r * 612 + c] : 0.f);
    return;
  }
  idx -= 256 * KX_;
  if (idx < G4_ * HD_) { wih[idx] = f2bf(Wih[idx]); return; }
  idx -= G4_ * HD_;
  if (idx < G4_ * HD_ / 2) {  // fp8 pairs, k-linear
    int n = idx >> 7, c = (idx & 127) * 2;
    int pk = __builtin_amdgcn_cvt_pk_fp8_f32(Whh[n * 256 + c], Whh[n * 256 + c + 1],
                                             0, false);
    w8[((size_t)n * 256 + c) >> 1] = (u16)(pk & 0xffff);
    return;
  }
  idx -= G4_ * HD_ / 2;
  if (idx < LPAD_ * KO_) {
    int r = idx / KO_;
    wlin[idx] = f2bf(r < LBL_ ? linW[idx] : 0.f);
    return;
  }
  idx -= LPAD_ * KO_;
  if (idx < G4_) biasg[idx] = bih[idx] + bhh[idx];
}

// ---------------- K1: prefix sums ----------------
__global__ __launch_bounds__(256) void k_prefix(const float* enc, float* P) {
  int id = blockIdx.x * 256 + threadIdx.x;
  int b = id >> 9, d = id & 511;
  const float* e = enc + (size_t)b * T_ * D2_ + d;
  float* p = P + (size_t)b * T_ * D2_ + d;
  float acc = 0.f;
  for (int t = 0; t < T_; ++t) {
    p[(size_t)t * D2_] = acc;
    acc += e[(size_t)t * D2_];
  }
}

// ---------------- K2: X rows [pe(100) | avg(512) | pad(28)] bf16 -------------
__global__ __launch_bounds__(256) void k_xbuild(const float* P, const float* ptab,
                                                const int* pid, const int* sidx,
                                                u16* X) {
  int m = blockIdx.x;  // m = t*64 + b
  int t = m >> 6, b = m & 63;
  int pp = 0, ps = 0;
  if (t > 0) {
    pp = pid[(t - 1) * B_ + b];
    ps = sidx[(t - 1) * B_ + b];
  }
  bool valid = (ps >= 0) && (t > 0);
  int start = min(ps, t - 1);
  if (start < 0) start = 0;
  if (start > T_ - 1) start = T_ - 1;
  float invlen = 1.f / (float)max(t - start, 1);
  const float* Pt = P + ((size_t)b * T_ + t) * D2_;
  const float* Psrc = P + ((size_t)b * T_ + start) * D2_;
  u16* xr = X + (size_t)m * KX_;
  for (int k = threadIdx.x; k < KX_; k += 256) {
    float v;
    if (k < PD_) v = ptab[pp * PD_ + k];
    else if (k < 612) {
      int d = k - PD_;
      v = valid ? (Pt[d] - Psrc[d]) * invlen : 0.f;
    } else v = 0.f;
    xr[k] = f2bf(v);
  }
}

// ---------------- generic 64x64-tile bf16 MFMA GEMM: out = A @ Bw^T ----------
// MODE 0: Z = tanh(X@Wc^T + comb_b), zero rows m<64, bf16 out, N=256
// MODE 1: G = Z@Wih^T + biasg -> PERMUTED gate layout for k_seq, N=1024
// MODE 2: Out = [H|enc]@lin^T, f32 out to d_out (cols<96), -1e10 fixup
template <int MODE>
__global__ __launch_bounds__(256) void k_gemm(const u16* A, const float* A2f,
                                              const u16* Bw, int K, int lda,
                                              const float* bias, u16* outb,
                                              float* outf) {
  __shared__ u16 As[64][40];
  __shared__ u16 Bs[64][40];
  const int m0 = blockIdx.x * 64, n0 = blockIdx.y * 64;
  const int tid = threadIdx.x;
  const int srow = tid >> 2, sc8 = (tid & 3) * 8;
  const int w = tid >> 6, l = tid & 63;
  const int l15 = l & 15, lh = l >> 4;
  f32x4 acc[4] = {};
  for (int k0 = 0; k0 < K; k0 += 32) {
    int k = k0 + sc8;
    uint4 av;
    if constexpr (MODE == 2) {
      if (k < 256) {
        av = *(const uint4*)(A + (size_t)(m0 + srow) * 256 + k);
      } else {
        const float* src = A2f + (size_t)(m0 + srow) * 512 + (k - 256);
        float4 f0 = *(const float4*)(src);
        float4 f1 = *(const float4*)(src + 4);
        av.x = (u32)f2bf(f0.x) | ((u32)f2bf(f0.y) << 16);
        av.y = (u32)f2bf(f0.z) | ((u32)f2bf(f0.w) << 16);
        av.z = (u32)f2bf(f1.x) | ((u32)f2bf(f1.y) << 16);
        av.w = (u32)f2bf(f1.z) | ((u32)f2bf(f1.w) << 16);
      }
    } else {
      av = *(const uint4*)(A + (size_t)(m0 + srow) * lda + k);
    }
    *(uint4*)&As[srow][sc8] = av;
    uint4 bv;
    if constexpr (MODE == 1) {
      int n = ((srow >> 4) << 8) + (int)blockIdx.y * 16 + (srow & 15);
      bv = *(const uint4*)(Bw + (size_t)n * K + k);
    } else {
      bv = *(const uint4*)(Bw + (size_t)(n0 + srow) * K + k);
    }
    *(uint4*)&Bs[srow][sc8] = bv;
    __syncthreads();
    short8 a8 = *(const short8*)&As[16 * w + l15][lh * 8];
#pragma unroll
    for (int nt = 0; nt < 4; ++nt) {
      short8 b8 = *(const short8*)&Bs[nt * 16 + l15][lh * 8];
      acc[nt] = __builtin_amdgcn_mfma_f32_16x16x32_bf16(a8, b8, acc[nt], 0, 0, 0);
    }
    __syncthreads();
  }
#pragma unroll
  for (int nt = 0; nt < 4; ++nt) {
#pragma unroll
    for (int r = 0; r < 4; ++r) {
      int gm = m0 + 16 * w + lh * 4 + r;
      float v = acc[nt][r];
      if constexpr (MODE == 0) {
        int gn = n0 + nt * 16 + l15;
        v = tanhf(v + bias[gn]);
        if (gm < 64) v = 0.f;
        outb[(size_t)gm * 256 + gn] = f2bf(v);
      } else if constexpr (MODE == 1) {
        int q = blockIdx.y;
        int na = nt * 256 + q * 16 + l15;
        v += bias[na];
        int j = (((q >> 1) * 16 + l15) << 3) + ((q & 1) << 2) + nt;
        outb[(size_t)gm * 1024 + j] = f2bf(v);
      } else {
        int gn = n0 + nt * 16 + l15;
        if (gn < LBL_) {
          if ((gm & (T_ - 1)) == 0 && gn == 1) v = -1e10f;
          outf[(size_t)gm * LBL_ + gn] = v;
        }
      }
    }
  }
}

// ---------------- K5: sequential LSTM via MX-scaled fp8 MFMA (K=128) ---------
// 8 waves (2/SIMD -> 256-reg cap). Wave w owns cells [w*32, w*32+32):
// 2 cell-tiles x 4 gates x 2 K-blocks = 128 VGPRs of B-frags, resident.
// Unit e8m0 scales (0x7f) -> numerics identical to non-scaled fp8, at the
// MX rate (~8.6 cyc/instr/CU vs 4x4.9 for the K=32 path).
__global__ __launch_bounds__(512, 2) void k_seq(const u16* G, const u16* w8,
                                                u16* Hout) {
  __shared__ __align__(16) unsigned char hq[2][256];
  const int b = blockIdx.x;
  const int tid = threadIdx.x;
  const int w = tid >> 6, l = tid & 63;
  const int c16 = l & 15, quad = l >> 4;
  const int cA = w * 32 + c16, cB = cA + 16;
  const unsigned char* w8b = (const unsigned char*)w8;
  i32x8 Bf[2][4][2];
#pragma unroll
  for (int ct = 0; ct < 2; ++ct)
#pragma unroll
    for (int g = 0; g < 4; ++g) {
      int n = g * 256 + w * 32 + ct * 16 + c16;
#pragma unroll
      for (int kb = 0; kb < 2; ++kb) {
        const uint4* p = (const uint4*)(w8b + (size_t)n * 256 + kb * 128 + quad * 32);
        uint4 x0 = p[0], x1 = p[1];
        Bf[ct][g][kb] = (i32x8){(int)x0.x, (int)x0.y, (int)x0.z, (int)x0.w,
                                (int)x1.x, (int)x1.y, (int)x1.z, (int)x1.w};
      }
    }
  if (tid < 256) hq[0][tid] = 0;
  const u16* gbase = G + (size_t)b * 1024 + (size_t)(w * 16 + c16) * 8;
  uint4 gv = *(const uint4*)gbase;
  float cc0 = 0.f, cc1 = 0.f;
  int cur = 0;
  __syncthreads();
  for (int t = 0; t < T_; ++t) {
    int tn = (t + 1 < T_) ? t + 1 : t;
    uint4 ngv = *(const uint4*)(gbase + (size_t)tn * 65536);
    // A-frags: h broadcast across rows; lane bytes = h[kb*128 + quad*32 .. +32)
    uint4 a0 = *(const uint4*)&hq[cur][quad * 32];
    uint4 a1 = *(const uint4*)&hq[cur][quad * 32 + 16];
    uint4 a2 = *(const uint4*)&hq[cur][128 + quad * 32];
    uint4 a3 = *(const uint4*)&hq[cur][128 + quad * 32 + 16];
    i32x8 A0 = (i32x8){(int)a0.x, (int)a0.y, (int)a0.z, (int)a0.w,
                       (int)a1.x, (int)a1.y, (int)a1.z, (int)a1.w};
    i32x8 A1 = (i32x8){(int)a2.x, (int)a2.y, (int)a2.z, (int)a2.w,
                       (int)a3.x, (int)a3.y, (int)a3.z, (int)a3.w};
    f32x4 acc[2][4];
    {
      float g0 = bf2f((u16)(gv.x & 0xffff)), g1 = bf2f((u16)(gv.x >> 16));
      float g2 = bf2f((u16)(gv.y & 0xffff)), g3 = bf2f((u16)(gv.y >> 16));
      float g4 = bf2f((u16)(gv.z & 0xffff)), g5 = bf2f((u16)(gv.z >> 16));
      float g6 = bf2f((u16)(gv.w & 0xffff)), g7 = bf2f((u16)(gv.w >> 16));
      acc[0][0] = (f32x4){g0, g0, g0, g0};
      acc[0][1] = (f32x4){g1, g1, g1, g1};
      acc[0][2] = (f32x4){g2, g2, g2, g2};
      acc[0][3] = (f32x4){g3, g3, g3, g3};
      acc[1][0] = (f32x4){g4, g4, g4, g4};
      acc[1][1] = (f32x4){g5, g5, g5, g5};
      acc[1][2] = (f32x4){g6, g6, g6, g6};
      acc[1][3] = (f32x4){g7, g7, g7, g7};
    }
#pragma unroll
    for (int ct = 0; ct < 2; ++ct)
#pragma unroll
      for (int g = 0; g < 4; ++g) {
        acc[ct][g] = __builtin_amdgcn_mfma_scale_f32_16x16x128_f8f6f4(
            A0, Bf[ct][g][0], acc[ct][g], 0, 0, 0, SCONE, 0, SCONE);
        acc[ct][g] = __builtin_amdgcn_mfma_scale_f32_16x16x128_f8f6f4(
            A1, Bf[ct][g][1], acc[ct][g], 0, 0, 0, SCONE, 0, SCONE);
      }
    float gi0 = acc[0][0][0], gf0 = acc[0][1][0], gg0 = acc[0][2][0], go0 = acc[0][3][0];
    float gi1 = acc[1][0][0], gf1 = acc[1][1][0], gg1 = acc[1][2][0], go1 = acc[1][3][0];
    cc0 = sgm(gf0) * cc0 + sgm(gi0) * thh(gg0);
    cc1 = sgm(gf1) * cc1 + sgm(gi1) * thh(gg1);
    float h0 = sgm(go0) * thh(cc0);
    float h1 = sgm(go1) * thh(cc1);
    if (l < 16) {
      int p8 = __builtin_amdgcn_cvt_pk_fp8_f32(h0, h1, 0, false);
      hq[cur ^ 1][cA] = (unsigned char)(p8 & 0xff);
      hq[cur ^ 1][cB] = (unsigned char)((p8 >> 8) & 0xff);
      u16* ho = Hout + ((size_t)b * 1024 + t) * 256 + cA;
      ho[0] = f2bf(h0);
      ho[16] = f2bf(h1);
    }
    gv = ngv;
    cur ^= 1;
    __syncthreads();
  }
}

// ---------------- K7: in-place row log-softmax on d_out ----------------------
__global__ __launch_bounds__(256) void k_lsm(float* out) {
  int row = blockIdx.x * 4 + (threadIdx.x >> 6);
  int l = threadIdx.x & 63;
  float* r = out + (size_t)row * LBL_;
  float v0 = r[l];
  float v1 = (l < 32) ? r[64 + l] : -__builtin_inff();
  float mx = fmaxf(v0, v1);
#pragma unroll
  for (int s = 32; s; s >>= 1) mx = fmaxf(mx, __shfl_xor(mx, s));
  float s0 = expf(v0 - mx) + ((l < 32) ? expf(v1 - mx) : 0.f);
#pragma unroll
  for (int s = 32; s; s >>= 1) s0 += __shfl_xor(s0, s);
  float lg = logf(s0) + mx;
  r[l] = v0 - lg;
  if (l < 32) r[64 + l] = v1 - lg;
}

extern "C" void kernel_launch(void* const* d_in, const int* in_sizes, int n_in,
                              void* d_out, int out_size, void* d_ws, size_t ws_size,
                              hipStream_t stream) {
  const float* enc = (const float*)d_in[0];
  const float* ptab = (const float*)d_in[1];
  const float* Wih = (const float*)d_in[2];
  const float* bih = (const float*)d_in[3];
  const float* Whh = (const float*)d_in[4];
  const float* bhh = (const float*)d_in[5];
  const float* combW = (const float*)d_in[6];
  const float* combb = (const float*)d_in[7];
  const float* linW = (const float*)d_in[8];
  const int* pid = (const int*)d_in[9];
  const int* sidx = (const int*)d_in[10];

  char* ws = (char*)d_ws;
  size_t off = 0;
  auto alloc = [&](size_t bytes) {
    void* p = ws + off;
    off += (bytes + 255) & ~(size_t)255;
    return p;
  };
  float* P = (float*)alloc((size_t)B_ * T_ * D2_ * 4);  // -> aliased by G
  u16* Xb = (u16*)alloc((size_t)T_ * B_ * KX_ * 2);     // -> aliased by H
  u16* Z = (u16*)alloc((size_t)T_ * B_ * HD_ * 2);
  u16* wc = (u16*)alloc(256 * KX_ * 2);
  u16* wih = (u16*)alloc(G4_ * HD_ * 2);
  u16* w8 = (u16*)alloc(G4_ * HD_);  // fp8 bytes
  u16* wlin = (u16*)alloc(LPAD_ * KO_ * 2);
  float* biasg = (float*)alloc(G4_ * 4);
  u16* G = (u16*)P;
  u16* Hs = (u16*)Xb;
  float* out = (float*)d_out;

  k_prep<<<2564, 256, 0, stream>>>(combW, Wih, bih, Whh, bhh, linW, wc, wih, w8,
                                   wlin, biasg);
  k_prefix<<<128, 256, 0, stream>>>(enc, P);
  k_xbuild<<<T_ * B_, 256, 0, stream>>>(P, ptab, pid, sidx, Xb);
  dim3 g3(1024, 4);
  k_gemm<0><<<g3, 256, 0, stream>>>(Xb, nullptr, wc, KX_, KX_, combb, Z, nullptr);
  dim3 g4(1024, 16);
  k_gemm<1><<<g4, 256, 0, stream>>>(Z, nullptr, wih, HD_, HD_, biasg, G, nullptr);
  k_seq<<<B_, 512, 0, stream>>>(G, w8, Hs);
  dim3 g6(1024, 2);
  k_gemm<2><<<g6, 256, 0, stream>>>(Hs, enc, wlin, KO_, 0, nullptr, nullptr, out);
  k_lsm<<<(T_ * B_) / 4, 256, 0, stream>>>(out);
}

// Round 7
// 1401.607 us; speedup vs baseline: 3.6966x; 1.1603x over previous
//
#include <hip/hip_runtime.h>

typedef unsigned short u16;
typedef unsigned int u32;
typedef unsigned long long u64;
typedef __attribute__((ext_vector_type(8))) short short8;
typedef __attribute__((ext_vector_type(4))) float f32x4;
typedef __attribute__((ext_vector_type(8))) int i32x8;

#define B_ 64
#define T_ 1024
#define D2_ 512
#define HD_ 256
#define G4_ 1024
#define PD_ 100
#define KX_ 640
#define KO_ 768
#define LBL_ 96
#define LPAD_ 128
#define SCONE 0x7f7f7f7f  // e8m0 scale bytes: 2^0 = 1.0 in all 4 positions

__device__ __forceinline__ float bf2f(u16 u) {
  u32 v = ((u32)u) << 16;
  return __builtin_bit_cast(float, v);
}
__device__ __forceinline__ u16 f2bf(float f) {
  u32 u = __builtin_bit_cast(u32, f);
  u32 r = (u + 0x7fffu + ((u >> 16) & 1u)) >> 16;
  return (u16)r;
}
__device__ __forceinline__ u32 pk2(float a, float b) {
  return (u32)f2bf(a) | ((u32)f2bf(b) << 16);
}
__device__ __forceinline__ float sgm(float x) {
  return __builtin_amdgcn_rcpf(1.f + __builtin_amdgcn_exp2f(-1.442695040888963f * x));
}
__device__ __forceinline__ float thh(float x) {
  return fmaf(-2.f,
              __builtin_amdgcn_rcpf(1.f + __builtin_amdgcn_exp2f(2.885390081777927f * x)),
              1.f);
}

// ---------------- K0: weight prep ----------------
// wc: comb_W bf16 [256][640] padded; wih: W_ih bf16; w8: W_hh fp8 e4m3
// [1024][256] k-linear; wlin: lin_W bf16 [128][768]; biasg = b_ih + b_hh
__global__ __launch_bounds__(256) void k_prep(
    const float* combW, const float* Wih, const float* bih, const float* Whh,
    const float* bhh, const float* linW, u16* wc, u16* wih, u16* w8, u16* wlin,
    float* biasg) {
  int idx = blockIdx.x * 256 + threadIdx.x;
  if (idx < 256 * KX_) {
    int r = idx / KX_, c = idx % KX_;
    wc[idx] = f2bf(c < 612 ? combW[r * 612 + c] : 0.f);
    return;
  }
  idx -= 256 * KX_;
  if (idx < G4_ * HD_) { wih[idx] = f2bf(Wih[idx]); return; }
  idx -= G4_ * HD_;
  if (idx < G4_ * HD_ / 2) {  // fp8 pairs, k-linear
    int n = idx >> 7, c = (idx & 127) * 2;
    int pk = __builtin_amdgcn_cvt_pk_fp8_f32(Whh[n * 256 + c], Whh[n * 256 + c + 1],
                                             0, false);
    w8[((size_t)n * 256 + c) >> 1] = (u16)(pk & 0xffff);
    return;
  }
  idx -= G4_ * HD_ / 2;
  if (idx < LPAD_ * KO_) {
    int r = idx / KO_;
    wlin[idx] = f2bf(r < LBL_ ? linW[idx] : 0.f);
    return;
  }
  idx -= LPAD_ * KO_;
  if (idx < G4_) biasg[idx] = bih[idx] + bhh[idx];
}

// ---------------- K1: prefix sums ----------------
__global__ __launch_bounds__(256) void k_prefix(const float* enc, float* P) {
  int id = blockIdx.x * 256 + threadIdx.x;
  int b = id >> 9, d = id & 511;
  const float* e = enc + (size_t)b * T_ * D2_ + d;
  float* p = P + (size_t)b * T_ * D2_ + d;
  float acc = 0.f;
  for (int t = 0; t < T_; ++t) {
    p[(size_t)t * D2_] = acc;
    acc += e[(size_t)t * D2_];
  }
}

// ---------------- K2: X rows [pe(100) | avg(512) | pad(28)] bf16 -------------
// 320 threads = 4 rows x 80 chunk-threads; each thread packs 8 elems (uint4).
__global__ __launch_bounds__(320) void k_xbuild(const float* P, const float* ptab,
                                                const int* pid, const int* sidx,
                                                u16* X) {
  const int tid = threadIdx.x;
  const int row = tid / 80;
  const int ir = tid - row * 80;
  const int m = blockIdx.x * 4 + row;  // m = t*64 + b
  const int t = m >> 6, b = m & 63;
  int pp = 0, ps = 0;
  if (t > 0) {
    pp = pid[(t - 1) * B_ + b];
    ps = sidx[(t - 1) * B_ + b];
  }
  bool valid = (ps >= 0) && (t > 0);
  int start = min(ps, t - 1);
  start = max(start, 0);
  start = min(start, T_ - 1);
  float invlen = 1.f / (float)max(t - start, 1);
  const float* Pt = P + ((size_t)b * T_ + t) * D2_;
  const float* Ps = P + ((size_t)b * T_ + start) * D2_;
  const int k0 = ir * 8;
  uint4 o;
  if (k0 >= 104 && k0 + 8 <= 612) {  // pure avg zone, 16B-aligned float4s
    if (valid) {
      int d = k0 - 100;
      float4 t0 = *(const float4*)(Pt + d), t1 = *(const float4*)(Pt + d + 4);
      float4 s0 = *(const float4*)(Ps + d), s1 = *(const float4*)(Ps + d + 4);
      o.x = pk2((t0.x - s0.x) * invlen, (t0.y - s0.y) * invlen);
      o.y = pk2((t0.z - s0.z) * invlen, (t0.w - s0.w) * invlen);
      o.z = pk2((t1.x - s1.x) * invlen, (t1.y - s1.y) * invlen);
      o.w = pk2((t1.z - s1.z) * invlen, (t1.w - s1.w) * invlen);
    } else {
      o = (uint4){0, 0, 0, 0};
    }
  } else if (k0 + 8 <= 100) {  // pure pos-table zone
    const float* pr = ptab + pp * PD_ + k0;
    o.x = pk2(pr[0], pr[1]);
    o.y = pk2(pr[2], pr[3]);
    o.z = pk2(pr[4], pr[5]);
    o.w = pk2(pr[6], pr[7]);
  } else if (k0 >= 616) {
    o = (uint4){0, 0, 0, 0};
  } else {  // mixed boundary chunks (ir == 12 or 76)
    u32 ow[4];
#pragma unroll
    for (int j2 = 0; j2 < 4; ++j2) {
      float v[2];
#pragma unroll
      for (int jj = 0; jj < 2; ++jj) {
        int k = k0 + j2 * 2 + jj;
        float x;
        if (k < PD_) x = ptab[pp * PD_ + k];
        else if (k < 612) x = valid ? (Pt[k - PD_] - Ps[k - PD_]) * invlen : 0.f;
        else x = 0.f;
        v[jj] = x;
      }
      ow[j2] = pk2(v[0], v[1]);
    }
    o = (uint4){ow[0], ow[1], ow[2], ow[3]};
  }
  *(uint4*)(X + (size_t)m * KX_ + k0) = o;
}

// ---------------- generic 64x64-tile bf16 MFMA GEMM: out = A @ Bw^T ----------
// MODE 0: Z = tanh(X@Wc^T + comb_b), zero rows m<64, bf16 out, N=256
// MODE 1: G = Z@Wih^T + biasg -> layout G[m][cell*4+gate] for k_seq, N=1024
template <int MODE>
__global__ __launch_bounds__(256) void k_gemm(const u16* A, const u16* Bw, int K,
                                              const float* bias, u16* outb) {
  __shared__ u16 As[64][40];
  __shared__ u16 Bs[64][40];
  const int m0 = blockIdx.x * 64, n0 = blockIdx.y * 64;
  const int tid = threadIdx.x;
  const int srow = tid >> 2, sc8 = (tid & 3) * 8;
  const int w = tid >> 6, l = tid & 63;
  const int l15 = l & 15, lh = l >> 4;
  f32x4 acc[4] = {};
  for (int k0 = 0; k0 < K; k0 += 32) {
    int k = k0 + sc8;
    uint4 av = *(const uint4*)(A + (size_t)(m0 + srow) * K + k);
    *(uint4*)&As[srow][sc8] = av;
    uint4 bv;
    if constexpr (MODE == 1) {
      int n = ((srow >> 4) << 8) + (int)blockIdx.y * 16 + (srow & 15);
      bv = *(const uint4*)(Bw + (size_t)n * K + k);
    } else {
      bv = *(const uint4*)(Bw + (size_t)(n0 + srow) * K + k);
    }
    *(uint4*)&Bs[srow][sc8] = bv;
    __syncthreads();
    short8 a8 = *(const short8*)&As[16 * w + l15][lh * 8];
#pragma unroll
    for (int nt = 0; nt < 4; ++nt) {
      short8 b8 = *(const short8*)&Bs[nt * 16 + l15][lh * 8];
      acc[nt] = __builtin_amdgcn_mfma_f32_16x16x32_bf16(a8, b8, acc[nt], 0, 0, 0);
    }
    __syncthreads();
  }
#pragma unroll
  for (int nt = 0; nt < 4; ++nt) {
#pragma unroll
    for (int r = 0; r < 4; ++r) {
      int gm = m0 + 16 * w + lh * 4 + r;
      float v = acc[nt][r];
      if constexpr (MODE == 0) {
        int gn = n0 + nt * 16 + l15;
        v = tanhf(v + bias[gn]);
        if (gm < 64) v = 0.f;
        outb[(size_t)gm * 256 + gn] = f2bf(v);
      } else {
        int q = blockIdx.y;
        int cell = q * 16 + l15;
        v += bias[nt * 256 + cell];
        outb[(size_t)gm * 1024 + cell * 4 + nt] = f2bf(v);
      }
    }
  }
}

// ---------------- K5: sequential LSTM via MX-scaled fp8 MFMA (K=128) ---------
// 8 waves. Wave w owns cells [w*32, w*32+32): 2 cell-tiles x 4 gates x 2
// K-blocks = 128 VGPRs of B-frags, resident. acc re-zeroed EVERY step
// (C=0; gate = dot + G-bias at readout) — no cross-step MFMA register
// feedback. Each thread updates ONE cell (quads 0-1 -> ct0, 2-3 -> ct1).
__global__ __launch_bounds__(512, 2) void k_seq(const u16* G, const u16* w8,
                                                u16* Hout) {
  __shared__ __align__(16) unsigned char hq[2][256];
  const int b = blockIdx.x;
  const int tid = threadIdx.x;
  const int w = tid >> 6, l = tid & 63;
  const int c16 = l & 15, quad = l >> 4;
  const unsigned char* w8b = (const unsigned char*)w8;
  i32x8 Bf[2][4][2];
#pragma unroll
  for (int ct = 0; ct < 2; ++ct)
#pragma unroll
    for (int g = 0; g < 4; ++g) {
      int n = g * 256 + w * 32 + ct * 16 + c16;
#pragma unroll
      for (int kb = 0; kb < 2; ++kb) {
        const uint4* p = (const uint4*)(w8b + (size_t)n * 256 + kb * 128 + quad * 32);
        uint4 x0 = p[0], x1 = p[1];
        Bf[ct][g][kb] = (i32x8){(int)x0.x, (int)x0.y, (int)x0.z, (int)x0.w,
                                (int)x1.x, (int)x1.y, (int)x1.z, (int)x1.w};
      }
    }
  if (tid < 256) hq[0][tid] = 0;
  const int myct = quad >> 1;
  const int mycell = w * 32 + myct * 16 + c16;
  const u16* gptr = G + (size_t)b * 1024 + mycell * 4;
  u64 gq = *(const u64*)gptr;
  float cc = 0.f;
  int cur = 0;
  __syncthreads();
  for (int t = 0; t < T_; ++t) {
    int tn = (t + 1 < T_) ? t + 1 : t;
    u64 ngq = *(const u64*)(gptr + (size_t)tn * 65536);
    uint4 a0 = *(const uint4*)&hq[cur][quad * 32];
    uint4 a1 = *(const uint4*)&hq[cur][quad * 32 + 16];
    uint4 a2 = *(const uint4*)&hq[cur][128 + quad * 32];
    uint4 a3 = *(const uint4*)&hq[cur][128 + quad * 32 + 16];
    i32x8 A0 = (i32x8){(int)a0.x, (int)a0.y, (int)a0.z, (int)a0.w,
                       (int)a1.x, (int)a1.y, (int)a1.z, (int)a1.w};
    i32x8 A1 = (i32x8){(int)a2.x, (int)a2.y, (int)a2.z, (int)a2.w,
                       (int)a3.x, (int)a3.y, (int)a3.z, (int)a3.w};
    f32x4 acc[2][4];
#pragma unroll
    for (int ct = 0; ct < 2; ++ct)
#pragma unroll
      for (int g = 0; g < 4; ++g) {
        f32x4 z4 = (f32x4){0.f, 0.f, 0.f, 0.f};
        z4 = __builtin_amdgcn_mfma_scale_f32_16x16x128_f8f6f4(
            A0, Bf[ct][g][0], z4, 0, 0, 0, SCONE, 0, SCONE);
        z4 = __builtin_amdgcn_mfma_scale_f32_16x16x128_f8f6f4(
            A1, Bf[ct][g][1], z4, 0, 0, 0, SCONE, 0, SCONE);
        acc[ct][g] = z4;
      }
    bool hi = (myct != 0);
    float vi = (hi ? acc[1][0][0] : acc[0][0][0]) + bf2f((u16)gq);
    float vf = (hi ? acc[1][1][0] : acc[0][1][0]) + bf2f((u16)(gq >> 16));
    float vg = (hi ? acc[1][2][0] : acc[0][2][0]) + bf2f((u16)(gq >> 32));
    float vo = (hi ? acc[1][3][0] : acc[0][3][0]) + bf2f((u16)(gq >> 48));
    cc = sgm(vf) * cc + sgm(vi) * thh(vg);
    float h = sgm(vo) * thh(cc);
    if ((quad & 1) == 0) {
      int p8 = __builtin_amdgcn_cvt_pk_fp8_f32(h, h, 0, false);
      hq[cur ^ 1][mycell] = (unsigned char)(p8 & 0xff);
      Hout[((size_t)b * 1024 + t) * 256 + mycell] = f2bf(h);
    }
    gq = ngq;
    cur ^= 1;
    __syncthreads();
  }
}

// ---------------- K6: fused output GEMM + log-softmax ------------------------
// Out rows = [H | enc] @ lin^T; M-tile 64, N=128 in ONE block (enc read once).
// Wave w: rows [16w,16w+16), all 8 N-tiles; logsoftmax over cols 0..95 via
// in-reg max/sum + 16-lane shfl reduction; -1e10 fixup on (t==0, col==1).
__global__ __launch_bounds__(256) void k_out(const u16* Hs, const float* enc,
                                             const u16* wlin, float* out) {
  __shared__ u16 As[64][40];
  __shared__ u16 Bs[128][40];
  const int m0 = blockIdx.x * 64;
  const int tid = threadIdx.x;
  const int srow = tid >> 2, sc8 = (tid & 3) * 8;
  const int brow = tid >> 1, bc16 = (tid & 1) * 16;
  const int w = tid >> 6, l = tid & 63;
  const int l15 = l & 15, lh = l >> 4;
  f32x4 acc[8] = {};
  for (int k0 = 0; k0 < KO_; k0 += 32) {
    int k = k0 + sc8;
    uint4 av;
    if (k < 256) {
      av = *(const uint4*)(Hs + (size_t)(m0 + srow) * 256 + k);
    } else {
      const float* src = enc + (size_t)(m0 + srow) * 512 + (k - 256);
      float4 f0 = *(const float4*)(src);
      float4 f1 = *(const float4*)(src + 4);
      av.x = pk2(f0.x, f0.y);
      av.y = pk2(f0.z, f0.w);
      av.z = pk2(f1.x, f1.y);
      av.w = pk2(f1.z, f1.w);
    }
    *(uint4*)&As[srow][sc8] = av;
    const u16* bsrc = wlin + (size_t)brow * KO_ + k0 + bc16;
    *(uint4*)&Bs[brow][bc16] = *(const uint4*)(bsrc);
    *(uint4*)&Bs[brow][bc16 + 8] = *(const uint4*)(bsrc + 8);
    __syncthreads();
    short8 a8 = *(const short8*)&As[16 * w + l15][lh * 8];
#pragma unroll
    for (int nt = 0; nt < 8; ++nt) {
      short8 b8 = *(const short8*)&Bs[nt * 16 + l15][lh * 8];
      acc[nt] = __builtin_amdgcn_mfma_f32_16x16x32_bf16(a8, b8, acc[nt], 0, 0, 0);
    }
    __syncthreads();
  }
#pragma unroll
  for (int r = 0; r < 4; ++r) {
    int gm = m0 + 16 * w + lh * 4 + r;
    float v[8];
#pragma unroll
    for (int nt = 0; nt < 8; ++nt) v[nt] = acc[nt][r];
    if ((gm & (T_ - 1)) == 0 && l15 == 1) v[0] = -1e10f;  // t==0, col==APP_ID
    float mx = v[0];
#pragma unroll
    for (int nt = 1; nt < 6; ++nt) mx = fmaxf(mx, v[nt]);
#pragma unroll
    for (int s = 1; s < 16; s <<= 1) mx = fmaxf(mx, __shfl_xor(mx, s));
    float s0 = 0.f;
#pragma unroll
    for (int nt = 0; nt < 6; ++nt)
      s0 += __builtin_amdgcn_exp2f(1.442695040888963f * (v[nt] - mx));
#pragma unroll
    for (int s = 1; s < 16; s <<= 1) s0 += __shfl_xor(s0, s);
    float lg = __builtin_amdgcn_logf(s0) * 0.6931471805599453f + mx;
#pragma unroll
    for (int nt = 0; nt < 6; ++nt)
      out[(size_t)gm * LBL_ + nt * 16 + l15] = v[nt] - lg;
  }
}

extern "C" void kernel_launch(void* const* d_in, const int* in_sizes, int n_in,
                              void* d_out, int out_size, void* d_ws, size_t ws_size,
                              hipStream_t stream) {
  const float* enc = (const float*)d_in[0];
  const float* ptab = (const float*)d_in[1];
  const float* Wih = (const float*)d_in[2];
  const float* bih = (const float*)d_in[3];
  const float* Whh = (const float*)d_in[4];
  const float* bhh = (const float*)d_in[5];
  const float* combW = (const float*)d_in[6];
  const float* combb = (const float*)d_in[7];
  const float* linW = (const float*)d_in[8];
  const int* pid = (const int*)d_in[9];
  const int* sidx = (const int*)d_in[10];

  char* ws = (char*)d_ws;
  size_t off = 0;
  auto alloc = [&](size_t bytes) {
    void* p = ws + off;
    off += (bytes + 255) & ~(size_t)255;
    return p;
  };
  float* P = (float*)alloc((size_t)B_ * T_ * D2_ * 4);  // -> aliased by G
  u16* Xb = (u16*)alloc((size_t)T_ * B_ * KX_ * 2);     // -> aliased by H
  u16* Z = (u16*)alloc((size_t)T_ * B_ * HD_ * 2);
  u16* wc = (u16*)alloc(256 * KX_ * 2);
  u16* wih = (u16*)alloc(G4_ * HD_ * 2);
  u16* w8 = (u16*)alloc(G4_ * HD_);  // fp8 bytes
  u16* wlin = (u16*)alloc(LPAD_ * KO_ * 2);
  float* biasg = (float*)alloc(G4_ * 4);
  u16* G = (u16*)P;
  u16* Hs = (u16*)Xb;
  float* out = (float*)d_out;

  k_prep<<<2564, 256, 0, stream>>>(combW, Wih, bih, Whh, bhh, linW, wc, wih, w8,
                                   wlin, biasg);
  k_prefix<<<128, 256, 0, stream>>>(enc, P);
  k_xbuild<<<T_ * B_ / 4, 320, 0, stream>>>(P, ptab, pid, sidx, Xb);
  dim3 g3(1024, 4);
  k_gemm<0><<<g3, 256, 0, stream>>>(Xb, wc, KX_, combb, Z);
  dim3 g4(1024, 16);
  k_gemm<1><<<g4, 256, 0, stream>>>(Z, wih, HD_, biasg, G);
  k_seq<<<B_, 512, 0, stream>>>(G, w8, Hs);
  k_out<<<1024, 256, 0, stream>>>(Hs, enc, wlin, out);
}

// Round 8
// 1020.404 us; speedup vs baseline: 5.0775x; 1.3736x over previous
//
#include <hip/hip_runtime.h>

typedef unsigned short u16;
typedef unsigned int u32;
typedef unsigned long long u64;
typedef __attribute__((ext_vector_type(8))) short short8;
typedef __attribute__((ext_vector_type(4))) float f32x4;
typedef __attribute__((ext_vector_type(8))) int i32x8;

#define B_ 64
#define T_ 1024
#define D2_ 512
#define HD_ 256
#define G4_ 1024
#define PD_ 100
#define KX_ 640
#define KO_ 768
#define LBL_ 96
#define LPAD_ 128
#define SCONE 0x7f7f7f7f  // e8m0 scale bytes: 2^0 = 1.0 in all 4 positions

__device__ __forceinline__ float bf2f(u16 u) {
  u32 v = ((u32)u) << 16;
  return __builtin_bit_cast(float, v);
}
__device__ __forceinline__ u16 f2bf(float f) {
  u32 u = __builtin_bit_cast(u32, f);
  u32 r = (u + 0x7fffu + ((u >> 16) & 1u)) >> 16;
  return (u16)r;
}
__device__ __forceinline__ u32 pk2(float a, float b) {
  return (u32)f2bf(a) | ((u32)f2bf(b) << 16);
}
__device__ __forceinline__ float sgm(float x) {
  return __builtin_amdgcn_rcpf(1.f + __builtin_amdgcn_exp2f(-1.442695040888963f * x));
}
__device__ __forceinline__ float thh(float x) {
  return fmaf(-2.f,
              __builtin_amdgcn_rcpf(1.f + __builtin_amdgcn_exp2f(2.885390081777927f * x)),
              1.f);
}

// ---------------- K0: weight prep ----------------
// wc: comb_W bf16 [256][640] padded; wih: W_ih bf16; w8: W_hh fp8 e4m3
// [1024][256] k-linear; wlin: lin_W bf16 [128][768]; biasg = b_ih + b_hh
__global__ __launch_bounds__(256) void k_prep(
    const float* combW, const float* Wih, const float* bih, const float* Whh,
    const float* bhh, const float* linW, u16* wc, u16* wih, u16* w8, u16* wlin,
    float* biasg) {
  int idx = blockIdx.x * 256 + threadIdx.x;
  if (idx < 256 * KX_) {
    int r = idx / KX_, c = idx % KX_;
    wc[idx] = f2bf(c < 612 ? combW[r * 612 + c] : 0.f);
    return;
  }
  idx -= 256 * KX_;
  if (idx < G4_ * HD_) { wih[idx] = f2bf(Wih[idx]); return; }
  idx -= G4_ * HD_;
  if (idx < G4_ * HD_ / 2) {  // fp8 pairs, k-linear
    int n = idx >> 7, c = (idx & 127) * 2;
    int pk = __builtin_amdgcn_cvt_pk_fp8_f32(Whh[n * 256 + c], Whh[n * 256 + c + 1],
                                             0, false);
    w8[((size_t)n * 256 + c) >> 1] = (u16)(pk & 0xffff);
    return;
  }
  idx -= G4_ * HD_ / 2;
  if (idx < LPAD_ * KO_) {
    int r = idx / KO_;
    wlin[idx] = f2bf(r < LBL_ ? linW[idx] : 0.f);
    return;
  }
  idx -= LPAD_ * KO_;
  if (idx < G4_) biasg[idx] = bih[idx] + bhh[idx];
}

// ---------------- K1a: chunk sums S[b*16+c][d] = sum_{j<64} enc[b][c*64+j][d]
__global__ __launch_bounds__(512) void k_psum(const float* enc, float* S) {
  const int bc = blockIdx.x;  // b*16 + c
  const int d = threadIdx.x;
  const int b = bc >> 4, c = bc & 15;
  const float* e = enc + (((size_t)b * T_) + c * 64) * D2_ + d;
  float s = 0.f;
#pragma unroll 8
  for (int j = 0; j < 64; ++j) s += e[(size_t)j * D2_];
  S[(size_t)bc * D2_ + d] = s;
}

// ---------------- K1b: P[b][c*64+j][d] = chunk_offset + local exclusive scan
__global__ __launch_bounds__(512) void k_pwrite(const float* enc, const float* S,
                                                float* P) {
  const int bc = blockIdx.x;
  const int d = threadIdx.x;
  const int b = bc >> 4, c = bc & 15;
  float off = 0.f;
  for (int c2 = 0; c2 < c; ++c2) off += S[((size_t)(b * 16 + c2)) * D2_ + d];
  const float* e = enc + (((size_t)b * T_) + c * 64) * D2_ + d;
  float* p = P + (((size_t)b * T_) + c * 64) * D2_ + d;
#pragma unroll 4
  for (int j = 0; j < 64; ++j) {
    p[(size_t)j * D2_] = off;
    off += e[(size_t)j * D2_];
  }
}

// ---------------- K2: X rows [pe(100) | avg(512) | pad(28)] bf16 -------------
// 320 threads = 4 rows x 80 chunk-threads; each thread packs 8 elems (uint4).
__global__ __launch_bounds__(320) void k_xbuild(const float* P, const float* ptab,
                                                const int* pid, const int* sidx,
                                                u16* X) {
  const int tid = threadIdx.x;
  const int row = tid / 80;
  const int ir = tid - row * 80;
  const int m = blockIdx.x * 4 + row;  // m = t*64 + b
  const int t = m >> 6, b = m & 63;
  int pp = 0, ps = 0;
  if (t > 0) {
    pp = pid[(t - 1) * B_ + b];
    ps = sidx[(t - 1) * B_ + b];
  }
  bool valid = (ps >= 0) && (t > 0);
  int start = min(ps, t - 1);
  start = max(start, 0);
  start = min(start, T_ - 1);
  float invlen = 1.f / (float)max(t - start, 1);
  const float* Pt = P + ((size_t)b * T_ + t) * D2_;
  const float* Ps = P + ((size_t)b * T_ + start) * D2_;
  const int k0 = ir * 8;
  uint4 o;
  if (k0 >= 104 && k0 + 8 <= 612) {  // pure avg zone, 16B-aligned float4s
    if (valid) {
      int d = k0 - 100;
      float4 t0 = *(const float4*)(Pt + d), t1 = *(const float4*)(Pt + d + 4);
      float4 s0 = *(const float4*)(Ps + d), s1 = *(const float4*)(Ps + d + 4);
      o.x = pk2((t0.x - s0.x) * invlen, (t0.y - s0.y) * invlen);
      o.y = pk2((t0.z - s0.z) * invlen, (t0.w - s0.w) * invlen);
      o.z = pk2((t1.x - s1.x) * invlen, (t1.y - s1.y) * invlen);
      o.w = pk2((t1.z - s1.z) * invlen, (t1.w - s1.w) * invlen);
    } else {
      o = (uint4){0, 0, 0, 0};
    }
  } else if (k0 + 8 <= 100) {  // pure pos-table zone
    const float* pr = ptab + pp * PD_ + k0;
    o.x = pk2(pr[0], pr[1]);
    o.y = pk2(pr[2], pr[3]);
    o.z = pk2(pr[4], pr[5]);
    o.w = pk2(pr[6], pr[7]);
  } else if (k0 >= 616) {
    o = (uint4){0, 0, 0, 0};
  } else {  // mixed boundary chunks (ir == 12 or 76)
    u32 ow[4];
#pragma unroll
    for (int j2 = 0; j2 < 4; ++j2) {
      float v[2];
#pragma unroll
      for (int jj = 0; jj < 2; ++jj) {
        int k = k0 + j2 * 2 + jj;
        float x;
        if (k < PD_) x = ptab[pp * PD_ + k];
        else if (k < 612) x = valid ? (Pt[k - PD_] - Ps[k - PD_]) * invlen : 0.f;
        else x = 0.f;
        v[jj] = x;
      }
      ow[j2] = pk2(v[0], v[1]);
    }
    o = (uint4){ow[0], ow[1], ow[2], ow[3]};
  }
  *(uint4*)(X + (size_t)m * KX_ + k0) = o;
}

// ---------------- 128x128-tile bf16 MFMA GEMM: out = A @ Bw^T ----------------
// 4 waves in 2x2; per wave 4x4 frags of 16x16x32; LDS [128][40] (2-way max).
// MODE 0: Z = tanh(X@Wc^T + comb_b), zero rows m<64, bf16 out, N=256, K=640
// MODE 1: G = Z@Wih^T + biasg -> layout G[m][cell*4+gate], N=1024, K=256
//         (B-tile row jj maps to weight row (j&3)*256 + (j>>2), j = n0+jj)
template <int MODE>
__global__ __launch_bounds__(256, 2) void k_gemm(const u16* A, const u16* Bw,
                                                 const float* bias, u16* outb) {
  constexpr int K = (MODE == 0) ? KX_ : HD_;
  constexpr int NOUT = (MODE == 0) ? 256 : 1024;
  __shared__ u16 As[128][40];
  __shared__ u16 Bs[128][40];
  const int m0 = blockIdx.x * 128, n0 = blockIdx.y * 128;
  const int tid = threadIdx.x;
  const int w = tid >> 6, l = tid & 63;
  const int wr = w >> 1, wc = w & 1;
  const int l15 = l & 15, lh = l >> 4;
  const int srow = tid >> 2, sc8 = (tid & 3) * 8;
  int brow0, brow1;
  if constexpr (MODE == 1) {
    int j0 = n0 + srow, j1 = n0 + srow + 64;
    brow0 = (j0 & 3) * 256 + (j0 >> 2);
    brow1 = (j1 & 3) * 256 + (j1 >> 2);
  } else {
    brow0 = n0 + srow;
    brow1 = n0 + srow + 64;
  }
  f32x4 acc[4][4] = {};
  for (int k0 = 0; k0 < K; k0 += 32) {
    uint4 a0 = *(const uint4*)(A + (size_t)(m0 + srow) * K + k0 + sc8);
    uint4 a1 = *(const uint4*)(A + (size_t)(m0 + srow + 64) * K + k0 + sc8);
    uint4 b0 = *(const uint4*)(Bw + (size_t)brow0 * K + k0 + sc8);
    uint4 b1 = *(const uint4*)(Bw + (size_t)brow1 * K + k0 + sc8);
    __syncthreads();  // previous iter's LDS reads complete
    *(uint4*)&As[srow][sc8] = a0;
    *(uint4*)&As[srow + 64][sc8] = a1;
    *(uint4*)&Bs[srow][sc8] = b0;
    *(uint4*)&Bs[srow + 64][sc8] = b1;
    __syncthreads();
    short8 af[4], bf[4];
#pragma unroll
    for (int i = 0; i < 4; ++i) {
      af[i] = *(const short8*)&As[wr * 64 + i * 16 + l15][lh * 8];
      bf[i] = *(const short8*)&Bs[wc * 64 + i * 16 + l15][lh * 8];
    }
#pragma unroll
    for (int mi = 0; mi < 4; ++mi)
#pragma unroll
      for (int ni = 0; ni < 4; ++ni)
        acc[mi][ni] =
            __builtin_amdgcn_mfma_f32_16x16x32_bf16(af[mi], bf[ni], acc[mi][ni], 0, 0, 0);
  }
#pragma unroll
  for (int mi = 0; mi < 4; ++mi)
#pragma unroll
    for (int ni = 0; ni < 4; ++ni)
#pragma unroll
      for (int r = 0; r < 4; ++r) {
        int gm = m0 + wr * 64 + mi * 16 + lh * 4 + r;
        int gn = n0 + wc * 64 + ni * 16 + l15;
        float v = acc[mi][ni][r];
        if constexpr (MODE == 0) {
          v = tanhf(v + bias[gn]);
          if (gm < 64) v = 0.f;  // t == 0 rows
          outb[(size_t)gm * NOUT + gn] = f2bf(v);
        } else {
          v += bias[(gn & 3) * 256 + (gn >> 2)];
          outb[(size_t)gm * NOUT + gn] = f2bf(v);
        }
      }
}

// ---------------- K5: sequential LSTM via MX-scaled fp8 MFMA (K=128) ---------
// 8 waves. Wave w owns cells [w*32, w*32+32): 2 cell-tiles x 4 gates x 2
// K-blocks = 128 VGPRs of B-frags, resident. acc re-zeroed EVERY step
// (C=0; gate = dot + G-bias at readout). One cell per thread.
__global__ __launch_bounds__(512, 2) void k_seq(const u16* G, const u16* w8,
                                                u16* Hout) {
  __shared__ __align__(16) unsigned char hq[2][256];
  const int b = blockIdx.x;
  const int tid = threadIdx.x;
  const int w = tid >> 6, l = tid & 63;
  const int c16 = l & 15, quad = l >> 4;
  const unsigned char* w8b = (const unsigned char*)w8;
  i32x8 Bf[2][4][2];
#pragma unroll
  for (int ct = 0; ct < 2; ++ct)
#pragma unroll
    for (int g = 0; g < 4; ++g) {
      int n = g * 256 + w * 32 + ct * 16 + c16;
#pragma unroll
      for (int kb = 0; kb < 2; ++kb) {
        const uint4* p = (const uint4*)(w8b + (size_t)n * 256 + kb * 128 + quad * 32);
        uint4 x0 = p[0], x1 = p[1];
        Bf[ct][g][kb] = (i32x8){(int)x0.x, (int)x0.y, (int)x0.z, (int)x0.w,
                                (int)x1.x, (int)x1.y, (int)x1.z, (int)x1.w};
      }
    }
  if (tid < 256) hq[0][tid] = 0;
  const int myct = quad >> 1;
  const int mycell = w * 32 + myct * 16 + c16;
  const u16* gptr = G + (size_t)b * 1024 + mycell * 4;
  u64 gq = *(const u64*)gptr;
  float cc = 0.f;
  int cur = 0;
  __syncthreads();
  for (int t = 0; t < T_; ++t) {
    int tn = (t + 1 < T_) ? t + 1 : t;
    u64 ngq = *(const u64*)(gptr + (size_t)tn * 65536);
    uint4 a0 = *(const uint4*)&hq[cur][quad * 32];
    uint4 a1 = *(const uint4*)&hq[cur][quad * 32 + 16];
    uint4 a2 = *(const uint4*)&hq[cur][128 + quad * 32];
    uint4 a3 = *(const uint4*)&hq[cur][128 + quad * 32 + 16];
    i32x8 A0 = (i32x8){(int)a0.x, (int)a0.y, (int)a0.z, (int)a0.w,
                       (int)a1.x, (int)a1.y, (int)a1.z, (int)a1.w};
    i32x8 A1 = (i32x8){(int)a2.x, (int)a2.y, (int)a2.z, (int)a2.w,
                       (int)a3.x, (int)a3.y, (int)a3.z, (int)a3.w};
    f32x4 acc[2][4];
#pragma unroll
    for (int ct = 0; ct < 2; ++ct)
#pragma unroll
      for (int g = 0; g < 4; ++g) {
        f32x4 z4 = (f32x4){0.f, 0.f, 0.f, 0.f};
        z4 = __builtin_amdgcn_mfma_scale_f32_16x16x128_f8f6f4(
            A0, Bf[ct][g][0], z4, 0, 0, 0, SCONE, 0, SCONE);
        z4 = __builtin_amdgcn_mfma_scale_f32_16x16x128_f8f6f4(
            A1, Bf[ct][g][1], z4, 0, 0, 0, SCONE, 0, SCONE);
        acc[ct][g] = z4;
      }
    bool hi = (myct != 0);
    float vi = (hi ? acc[1][0][0] : acc[0][0][0]) + bf2f((u16)gq);
    float vf = (hi ? acc[1][1][0] : acc[0][1][0]) + bf2f((u16)(gq >> 16));
    float vg = (hi ? acc[1][2][0] : acc[0][2][0]) + bf2f((u16)(gq >> 32));
    float vo = (hi ? acc[1][3][0] : acc[0][3][0]) + bf2f((u16)(gq >> 48));
    cc = sgm(vf) * cc + sgm(vi) * thh(vg);
    float h = sgm(vo) * thh(cc);
    if ((quad & 1) == 0) {
      int p8 = __builtin_amdgcn_cvt_pk_fp8_f32(h, h, 0, false);
      hq[cur ^ 1][mycell] = (unsigned char)(p8 & 0xff);
      Hout[((size_t)b * 1024 + t) * 256 + mycell] = f2bf(h);
    }
    gq = ngq;
    cur ^= 1;
    __syncthreads();
  }
}

// ---------------- K6: fused output GEMM + log-softmax ------------------------
__global__ __launch_bounds__(256) void k_out(const u16* Hs, const float* enc,
                                             const u16* wlin, float* out) {
  __shared__ u16 As[64][40];
  __shared__ u16 Bs[128][40];
  const int m0 = blockIdx.x * 64;
  const int tid = threadIdx.x;
  const int srow = tid >> 2, sc8 = (tid & 3) * 8;
  const int brow = tid >> 1, bc16 = (tid & 1) * 16;
  const int w = tid >> 6, l = tid & 63;
  const int l15 = l & 15, lh = l >> 4;
  f32x4 acc[8] = {};
  for (int k0 = 0; k0 < KO_; k0 += 32) {
    int k = k0 + sc8;
    uint4 av;
    if (k < 256) {
      av = *(const uint4*)(Hs + (size_t)(m0 + srow) * 256 + k);
    } else {
      const float* src = enc + (size_t)(m0 + srow) * 512 + (k - 256);
      float4 f0 = *(const float4*)(src);
      float4 f1 = *(const float4*)(src + 4);
      av.x = pk2(f0.x, f0.y);
      av.y = pk2(f0.z, f0.w);
      av.z = pk2(f1.x, f1.y);
      av.w = pk2(f1.z, f1.w);
    }
    *(uint4*)&As[srow][sc8] = av;
    const u16* bsrc = wlin + (size_t)brow * KO_ + k0 + bc16;
    *(uint4*)&Bs[brow][bc16] = *(const uint4*)(bsrc);
    *(uint4*)&Bs[brow][bc16 + 8] = *(const uint4*)(bsrc + 8);
    __syncthreads();
    short8 a8 = *(const short8*)&As[16 * w + l15][lh * 8];
#pragma unroll
    for (int nt = 0; nt < 8; ++nt) {
      short8 b8 = *(const short8*)&Bs[nt * 16 + l15][lh * 8];
      acc[nt] = __builtin_amdgcn_mfma_f32_16x16x32_bf16(a8, b8, acc[nt], 0, 0, 0);
    }
    __syncthreads();
  }
#pragma unroll
  for (int r = 0; r < 4; ++r) {
    int gm = m0 + 16 * w + lh * 4 + r;
    float v[8];
#pragma unroll
    for (int nt = 0; nt < 8; ++nt) v[nt] = acc[nt][r];
    if ((gm & (T_ - 1)) == 0 && l15 == 1) v[0] = -1e10f;  // t==0, col==APP_ID
    float mx = v[0];
#pragma unroll
    for (int nt = 1; nt < 6; ++nt) mx = fmaxf(mx, v[nt]);
#pragma unroll
    for (int s = 1; s < 16; s <<= 1) mx = fmaxf(mx, __shfl_xor(mx, s));
    float s0 = 0.f;
#pragma unroll
    for (int nt = 0; nt < 6; ++nt)
      s0 += __builtin_amdgcn_exp2f(1.442695040888963f * (v[nt] - mx));
#pragma unroll
    for (int s = 1; s < 16; s <<= 1) s0 += __shfl_xor(s0, s);
    float lg = __builtin_amdgcn_logf(s0) * 0.6931471805599453f + mx;
#pragma unroll
    for (int nt = 0; nt < 6; ++nt)
      out[(size_t)gm * LBL_ + nt * 16 + l15] = v[nt] - lg;
  }
}

extern "C" void kernel_launch(void* const* d_in, const int* in_sizes, int n_in,
                              void* d_out, int out_size, void* d_ws, size_t ws_size,
                              hipStream_t stream) {
  const float* enc = (const float*)d_in[0];
  const float* ptab = (const float*)d_in[1];
  const float* Wih = (const float*)d_in[2];
  const float* bih = (const float*)d_in[3];
  const float* Whh = (const float*)d_in[4];
  const float* bhh = (const float*)d_in[5];
  const float* combW = (const float*)d_in[6];
  const float* combb = (const float*)d_in[7];
  const float* linW = (const float*)d_in[8];
  const int* pid = (const int*)d_in[9];
  const int* sidx = (const int*)d_in[10];

  char* ws = (char*)d_ws;
  size_t off = 0;
  auto alloc = [&](size_t bytes) {
    void* p = ws + off;
    off += (bytes + 255) & ~(size_t)255;
    return p;
  };
  float* P = (float*)alloc((size_t)B_ * T_ * D2_ * 4);  // -> aliased by G
  u16* Xb = (u16*)alloc((size_t)T_ * B_ * KX_ * 2);     // -> aliased by H
  u16* Z = (u16*)alloc((size_t)T_ * B_ * HD_ * 2);      // S (2MB) lives here first
  u16* wc = (u16*)alloc(256 * KX_ * 2);
  u16* wih = (u16*)alloc(G4_ * HD_ * 2);
  u16* w8 = (u16*)alloc(G4_ * HD_);  // fp8 bytes
  u16* wlin = (u16*)alloc(LPAD_ * KO_ * 2);
  float* biasg = (float*)alloc(G4_ * 4);
  u16* G = (u16*)P;
  u16* Hs = (u16*)Xb;
  float* S = (float*)Z;  // 1024*512 f32 = 2MB, dead before Z is written
  float* out = (float*)d_out;

  k_prep<<<2564, 256, 0, stream>>>(combW, Wih, bih, Whh, bhh, linW, wc, wih, w8,
                                   wlin, biasg);
  k_psum<<<B_ * 16, 512, 0, stream>>>(enc, S);
  k_pwrite<<<B_ * 16, 512, 0, stream>>>(enc, S, P);
  k_xbuild<<<T_ * B_ / 4, 320, 0, stream>>>(P, ptab, pid, sidx, Xb);
  dim3 g3(512, 2);
  k_gemm<0><<<g3, 256, 0, stream>>>(Xb, wc, combb, Z);
  dim3 g4(512, 8);
  k_gemm<1><<<g4, 256, 0, stream>>>(Z, wih, biasg, G);
  k_seq<<<B_, 512, 0, stream>>>(G, w8, Hs);
  k_out<<<1024, 256, 0, stream>>>(Hs, enc, wlin, out);
}

// Round 9
// 906.115 us; speedup vs baseline: 5.7180x; 1.1261x over previous
//
#include <hip/hip_runtime.h>

typedef unsigned short u16;
typedef unsigned int u32;
typedef unsigned long long u64;
typedef __attribute__((ext_vector_type(8))) short short8;
typedef __attribute__((ext_vector_type(4))) float f32x4;
typedef __attribute__((ext_vector_type(8))) int i32x8;

#define B_ 64
#define T_ 1024
#define D2_ 512
#define HD_ 256
#define G4_ 1024
#define PD_ 100
#define KX_ 640
#define KO_ 768
#define LBL_ 96
#define LPAD_ 128
// e8m0 scale bytes (opsel=0 -> byte 0): A stored = h*4 -> 2^-2 (125);
// B stored = w*8 -> 2^-3 (124)
#define SCA 125
#define SCB 124

__device__ __forceinline__ float bf2f(u16 u) {
  u32 v = ((u32)u) << 16;
  return __builtin_bit_cast(float, v);
}
__device__ __forceinline__ u16 f2bf(float f) {
  u32 u = __builtin_bit_cast(u32, f);
  u32 r = (u + 0x7fffu + ((u >> 16) & 1u)) >> 16;
  return (u16)r;
}
__device__ __forceinline__ u32 pk2(float a, float b) {
  return (u32)f2bf(a) | ((u32)f2bf(b) << 16);
}
__device__ __forceinline__ float sgm(float x) {
  return __builtin_amdgcn_rcpf(1.f + __builtin_amdgcn_exp2f(-1.442695040888963f * x));
}
__device__ __forceinline__ float thh(float x) {
  return fmaf(-2.f,
              __builtin_amdgcn_rcpf(1.f + __builtin_amdgcn_exp2f(2.885390081777927f * x)),
              1.f);
}
// fp4 e2m1 encode of pre-scaled y (values {0,.5,1,1.5,2,3,4,6}), round-nearest
__device__ __forceinline__ u32 enc4(float y) {
  float a = fabsf(y);
  u32 c = 0;
  c = a >= 0.25f ? 1u : c;
  c = a >= 0.75f ? 2u : c;
  c = a >= 1.25f ? 3u : c;
  c = a >= 1.75f ? 4u : c;
  c = a >= 2.5f ? 5u : c;
  c = a >= 3.5f ? 6u : c;
  c = a >= 5.0f ? 7u : c;
  return c | ((__builtin_bit_cast(u32, y) >> 28) & 8u);
}

// ---------------- K0: weight prep ----------------
// wc: comb_W bf16 [256][640] padded; wih: W_ih bf16; w4: W_hh fp4 e2m1
// nibbles [1024][128B] (w*8, scale 2^-3); wlin: lin_W bf16 [128][768];
// biasg = b_ih + b_hh
__global__ __launch_bounds__(256) void k_prep(
    const float* combW, const float* Wih, const float* bih, const float* Whh,
    const float* bhh, const float* linW, u16* wc, u16* wih, u32* w4, u16* wlin,
    float* biasg) {
  int idx = blockIdx.x * 256 + threadIdx.x;
  if (idx < 256 * KX_) {
    int r = idx / KX_, c = idx % KX_;
    wc[idx] = f2bf(c < 612 ? combW[r * 612 + c] : 0.f);
    return;
  }
  idx -= 256 * KX_;
  if (idx < G4_ * HD_) { wih[idx] = f2bf(Wih[idx]); return; }
  idx -= G4_ * HD_;
  if (idx < G4_ * HD_ / 8) {  // 8 weights -> 1 u32 of nibbles (elem k at nibble k)
    int n = idx >> 5, c0 = (idx & 31) * 8;
    const float* wr = Whh + n * 256 + c0;
    u32 word = 0;
#pragma unroll
    for (int i = 0; i < 4; ++i) {
      u32 byte = enc4(wr[2 * i] * 8.f) | (enc4(wr[2 * i + 1] * 8.f) << 4);
      word |= byte << (8 * i);
    }
    w4[n * 32 + (c0 >> 3)] = word;
    return;
  }
  idx -= G4_ * HD_ / 8;
  if (idx < LPAD_ * KO_) {
    int r = idx / KO_;
    wlin[idx] = f2bf(r < LBL_ ? linW[idx] : 0.f);
    return;
  }
  idx -= LPAD_ * KO_;
  if (idx < G4_) biasg[idx] = bih[idx] + bhh[idx];
}

// ---------------- K1a: chunk sums S[b*16+c][d] = sum_{j<64} enc[b][c*64+j][d]
__global__ __launch_bounds__(512) void k_psum(const float* enc, float* S) {
  const int bc = blockIdx.x;  // b*16 + c
  const int d = threadIdx.x;
  const int b = bc >> 4, c = bc & 15;
  const float* e = enc + (((size_t)b * T_) + c * 64) * D2_ + d;
  float s = 0.f;
#pragma unroll 8
  for (int j = 0; j < 64; ++j) s += e[(size_t)j * D2_];
  S[(size_t)bc * D2_ + d] = s;
}

// ---------------- K1b: P[b][c*64+j][d] = chunk_offset + local exclusive scan
__global__ __launch_bounds__(512) void k_pwrite(const float* enc, const float* S,
                                                float* P) {
  const int bc = blockIdx.x;
  const int d = threadIdx.x;
  const int b = bc >> 4, c = bc & 15;
  float off = 0.f;
  for (int c2 = 0; c2 < c; ++c2) off += S[((size_t)(b * 16 + c2)) * D2_ + d];
  const float* e = enc + (((size_t)b * T_) + c * 64) * D2_ + d;
  float* p = P + (((size_t)b * T_) + c * 64) * D2_ + d;
#pragma unroll 4
  for (int j = 0; j < 64; ++j) {
    p[(size_t)j * D2_] = off;
    off += e[(size_t)j * D2_];
  }
}

// ---------------- K2: X rows [pe(100) | avg(512) | pad(28)] bf16 -------------
// 320 threads = 4 rows x 80 chunk-threads; each thread packs 8 elems (uint4).
__global__ __launch_bounds__(320) void k_xbuild(const float* P, const float* ptab,
                                                const int* pid, const int* sidx,
                                                u16* X) {
  const int tid = threadIdx.x;
  const int row = tid / 80;
  const int ir = tid - row * 80;
  const int m = blockIdx.x * 4 + row;  // m = t*64 + b
  const int t = m >> 6, b = m & 63;
  int pp = 0, ps = 0;
  if (t > 0) {
    pp = pid[(t - 1) * B_ + b];
    ps = sidx[(t - 1) * B_ + b];
  }
  bool valid = (ps >= 0) && (t > 0);
  int start = min(ps, t - 1);
  start = max(start, 0);
  start = min(start, T_ - 1);
  float invlen = 1.f / (float)max(t - start, 1);
  const float* Pt = P + ((size_t)b * T_ + t) * D2_;
  const float* Ps = P + ((size_t)b * T_ + start) * D2_;
  const int k0 = ir * 8;
  uint4 o;
  if (k0 >= 104 && k0 + 8 <= 612) {  // pure avg zone, 16B-aligned float4s
    if (valid) {
      int d = k0 - 100;
      float4 t0 = *(const float4*)(Pt + d), t1 = *(const float4*)(Pt + d + 4);
      float4 s0 = *(const float4*)(Ps + d), s1 = *(const float4*)(Ps + d + 4);
      o.x = pk2((t0.x - s0.x) * invlen, (t0.y - s0.y) * invlen);
      o.y = pk2((t0.z - s0.z) * invlen, (t0.w - s0.w) * invlen);
      o.z = pk2((t1.x - s1.x) * invlen, (t1.y - s1.y) * invlen);
      o.w = pk2((t1.z - s1.z) * invlen, (t1.w - s1.w) * invlen);
    } else {
      o = (uint4){0, 0, 0, 0};
    }
  } else if (k0 + 8 <= 100) {  // pure pos-table zone
    const float* pr = ptab + pp * PD_ + k0;
    o.x = pk2(pr[0], pr[1]);
    o.y = pk2(pr[2], pr[3]);
    o.z = pk2(pr[4], pr[5]);
    o.w = pk2(pr[6], pr[7]);
  } else if (k0 >= 616) {
    o = (uint4){0, 0, 0, 0};
  } else {  // mixed boundary chunks (ir == 12 or 76)
    u32 ow[4];
#pragma unroll
    for (int j2 = 0; j2 < 4; ++j2) {
      float v[2];
#pragma unroll
      for (int jj = 0; jj < 2; ++jj) {
        int k = k0 + j2 * 2 + jj;
        float x;
        if (k < PD_) x = ptab[pp * PD_ + k];
        else if (k < 612) x = valid ? (Pt[k - PD_] - Ps[k - PD_]) * invlen : 0.f;
        else x = 0.f;
        v[jj] = x;
      }
      ow[j2] = pk2(v[0], v[1]);
    }
    o = (uint4){ow[0], ow[1], ow[2], ow[3]};
  }
  *(uint4*)(X + (size_t)m * KX_ + k0) = o;
}

// ---------------- 128x128-tile bf16 MFMA GEMM: out = A @ Bw^T ----------------
// MODE 0: Z = tanh(X@Wc^T + comb_b), zero rows m<64, bf16 out, N=256, K=640
// MODE 1: G = Z@Wih^T + biasg -> layout G[m][cell*4+gate], N=1024, K=256
template <int MODE>
__global__ __launch_bounds__(256, 2) void k_gemm(const u16* A, const u16* Bw,
                                                 const float* bias, u16* outb) {
  constexpr int K = (MODE == 0) ? KX_ : HD_;
  constexpr int NOUT = (MODE == 0) ? 256 : 1024;
  __shared__ u16 As[128][40];
  __shared__ u16 Bs[128][40];
  const int m0 = blockIdx.x * 128, n0 = blockIdx.y * 128;
  const int tid = threadIdx.x;
  const int w = tid >> 6, l = tid & 63;
  const int wr = w >> 1, wc = w & 1;
  const int l15 = l & 15, lh = l >> 4;
  const int srow = tid >> 2, sc8 = (tid & 3) * 8;
  int brow0, brow1;
  if constexpr (MODE == 1) {
    int j0 = n0 + srow, j1 = n0 + srow + 64;
    brow0 = (j0 & 3) * 256 + (j0 >> 2);
    brow1 = (j1 & 3) * 256 + (j1 >> 2);
  } else {
    brow0 = n0 + srow;
    brow1 = n0 + srow + 64;
  }
  f32x4 acc[4][4] = {};
  for (int k0 = 0; k0 < K; k0 += 32) {
    uint4 a0 = *(const uint4*)(A + (size_t)(m0 + srow) * K + k0 + sc8);
    uint4 a1 = *(const uint4*)(A + (size_t)(m0 + srow + 64) * K + k0 + sc8);
    uint4 b0 = *(const uint4*)(Bw + (size_t)brow0 * K + k0 + sc8);
    uint4 b1 = *(const uint4*)(Bw + (size_t)brow1 * K + k0 + sc8);
    __syncthreads();  // previous iter's LDS reads complete
    *(uint4*)&As[srow][sc8] = a0;
    *(uint4*)&As[srow + 64][sc8] = a1;
    *(uint4*)&Bs[srow][sc8] = b0;
    *(uint4*)&Bs[srow + 64][sc8] = b1;
    __syncthreads();
    short8 af[4], bf[4];
#pragma unroll
    for (int i = 0; i < 4; ++i) {
      af[i] = *(const short8*)&As[wr * 64 + i * 16 + l15][lh * 8];
      bf[i] = *(const short8*)&Bs[wc * 64 + i * 16 + l15][lh * 8];
    }
#pragma unroll
    for (int mi = 0; mi < 4; ++mi)
#pragma unroll
      for (int ni = 0; ni < 4; ++ni)
        acc[mi][ni] =
            __builtin_amdgcn_mfma_f32_16x16x32_bf16(af[mi], bf[ni], acc[mi][ni], 0, 0, 0);
  }
#pragma unroll
  for (int mi = 0; mi < 4; ++mi)
#pragma unroll
    for (int ni = 0; ni < 4; ++ni)
#pragma unroll
      for (int r = 0; r < 4; ++r) {
        int gm = m0 + wr * 64 + mi * 16 + lh * 4 + r;
        int gn = n0 + wc * 64 + ni * 16 + l15;
        float v = acc[mi][ni][r];
        if constexpr (MODE == 0) {
          v = tanhf(v + bias[gn]);
          if (gm < 64) v = 0.f;  // t == 0 rows
          outb[(size_t)gm * NOUT + gn] = f2bf(v);
        } else {
          v += bias[(gn & 3) * 256 + (gn >> 2)];
          outb[(size_t)gm * NOUT + gn] = f2bf(v);
        }
      }
}

// ---------------- K5: sequential LSTM via MX fp4 MFMA (K=128, 2x rate) -------
// 8 waves. Wave w owns cells [w*32, w*32+32): 2ct x 4g x 2kb B-frags as fp4
// nibbles = 64 VGPRs. h kept as fp4 nibbles in LDS (128 B/buffer); both
// operands fp4 e2m1 (cbsz=4, blgp=4) -> 5.57 cy/instr class. acc re-zeroed
// every step; gate = dot + G-bias at readout. One cell per thread.
__global__ __launch_bounds__(512, 2) void k_seq(const u16* G, const u32* w4,
                                                u16* Hout) {
  __shared__ __align__(16) unsigned char hq[2][128];
  const int b = blockIdx.x;
  const int tid = threadIdx.x;
  const int w = tid >> 6, l = tid & 63;
  const int c16 = l & 15, quad = l >> 4;
  const unsigned char* w4b = (const unsigned char*)w4;
  uint4 Bf[2][4][2];
#pragma unroll
  for (int ct = 0; ct < 2; ++ct)
#pragma unroll
    for (int g = 0; g < 4; ++g) {
      int n = g * 256 + w * 32 + ct * 16 + c16;
#pragma unroll
      for (int kb = 0; kb < 2; ++kb)
        Bf[ct][g][kb] = *(const uint4*)(w4b + (size_t)n * 128 + kb * 64 + quad * 16);
    }
  if (tid < 128) hq[0][tid] = 0;
  const int myct = quad >> 1;
  const int mycell = w * 32 + myct * 16 + c16;
  const u16* gptr = G + (size_t)b * 1024 + mycell * 4;
  u64 gq = *(const u64*)gptr;
  float cc = 0.f;
  int cur = 0;
  __syncthreads();
  for (int t = 0; t < T_; ++t) {
    int tn = (t + 1 < T_) ? t + 1 : t;
    u64 ngq = *(const u64*)(gptr + (size_t)tn * 65536);
    uint4 a0 = *(const uint4*)&hq[cur][quad * 16];       // kb=0: k 0..127
    uint4 a1 = *(const uint4*)&hq[cur][64 + quad * 16];  // kb=1: k 128..255
    i32x8 A0 = (i32x8){(int)a0.x, (int)a0.y, (int)a0.z, (int)a0.w, 0, 0, 0, 0};
    i32x8 A1 = (i32x8){(int)a1.x, (int)a1.y, (int)a1.z, (int)a1.w, 0, 0, 0, 0};
    f32x4 acc[2][4];
#pragma unroll
    for (int ct = 0; ct < 2; ++ct)
#pragma unroll
      for (int g = 0; g < 4; ++g) {
        uint4 b0 = Bf[ct][g][0], b1 = Bf[ct][g][1];
        i32x8 B0 = (i32x8){(int)b0.x, (int)b0.y, (int)b0.z, (int)b0.w, 0, 0, 0, 0};
        i32x8 B1 = (i32x8){(int)b1.x, (int)b1.y, (int)b1.z, (int)b1.w, 0, 0, 0, 0};
        f32x4 z4 = (f32x4){0.f, 0.f, 0.f, 0.f};
        z4 = __builtin_amdgcn_mfma_scale_f32_16x16x128_f8f6f4(
            A0, B0, z4, 4, 4, 0, SCA, 0, SCB);
        z4 = __builtin_amdgcn_mfma_scale_f32_16x16x128_f8f6f4(
            A1, B1, z4, 4, 4, 0, SCA, 0, SCB);
        acc[ct][g] = z4;
      }
    bool hi = (myct != 0);
    float vi = (hi ? acc[1][0][0] : acc[0][0][0]) + bf2f((u16)gq);
    float vf = (hi ? acc[1][1][0] : acc[0][1][0]) + bf2f((u16)(gq >> 16));
    float vg = (hi ? acc[1][2][0] : acc[0][2][0]) + bf2f((u16)(gq >> 32));
    float vo = (hi ? acc[1][3][0] : acc[0][3][0]) + bf2f((u16)(gq >> 48));
    cc = sgm(vf) * cc + sgm(vi) * thh(vg);
    float h = sgm(vo) * thh(cc);
    u32 nib = enc4(h * 4.f);                       // h scale 2^-2
    u32 nib2 = (u32)__shfl_xor((int)nib, 1);       // neighbor cell's nibble
    if ((quad & 1) == 0) {
      if ((c16 & 1) == 0)
        hq[cur ^ 1][mycell >> 1] = (unsigned char)(nib | (nib2 << 4));
      Hout[((size_t)b * 1024 + t) * 256 + mycell] = f2bf(h);
    }
    gq = ngq;
    cur ^= 1;
    __syncthreads();
  }
}

// ---------------- K6: fused output GEMM + log-softmax ------------------------
__global__ __launch_bounds__(256) void k_out(const u16* Hs, const float* enc,
                                             const u16* wlin, float* out) {
  __shared__ u16 As[64][40];
  __shared__ u16 Bs[128][40];
  const int m0 = blockIdx.x * 64;
  const int tid = threadIdx.x;
  const int srow = tid >> 2, sc8 = (tid & 3) * 8;
  const int brow = tid >> 1, bc16 = (tid & 1) * 16;
  const int w = tid >> 6, l = tid & 63;
  const int l15 = l & 15, lh = l >> 4;
  f32x4 acc[8] = {};
  for (int k0 = 0; k0 < KO_; k0 += 32) {
    int k = k0 + sc8;
    uint4 av;
    if (k < 256) {
      av = *(const uint4*)(Hs + (size_t)(m0 + srow) * 256 + k);
    } else {
      const float* src = enc + (size_t)(m0 + srow) * 512 + (k - 256);
      float4 f0 = *(const float4*)(src);
      float4 f1 = *(const float4*)(src + 4);
      av.x = pk2(f0.x, f0.y);
      av.y = pk2(f0.z, f0.w);
      av.z = pk2(f1.x, f1.y);
      av.w = pk2(f1.z, f1.w);
    }
    *(uint4*)&As[srow][sc8] = av;
    const u16* bsrc = wlin + (size_t)brow * KO_ + k0 + bc16;
    *(uint4*)&Bs[brow][bc16] = *(const uint4*)(bsrc);
    *(uint4*)&Bs[brow][bc16 + 8] = *(const uint4*)(bsrc + 8);
    __syncthreads();
    short8 a8 = *(const short8*)&As[16 * w + l15][lh * 8];
#pragma unroll
    for (int nt = 0; nt < 8; ++nt) {
      short8 b8 = *(const short8*)&Bs[nt * 16 + l15][lh * 8];
      acc[nt] = __builtin_amdgcn_mfma_f32_16x16x32_bf16(a8, b8, acc[nt], 0, 0, 0);
    }
    __syncthreads();
  }
#pragma unroll
  for (int r = 0; r < 4; ++r) {
    int gm = m0 + 16 * w + lh * 4 + r;
    float v[8];
#pragma unroll
    for (int nt = 0; nt < 8; ++nt) v[nt] = acc[nt][r];
    if ((gm & (T_ - 1)) == 0 && l15 == 1) v[0] = -1e10f;  // t==0, col==APP_ID
    float mx = v[0];
#pragma unroll
    for (int nt = 1; nt < 6; ++nt) mx = fmaxf(mx, v[nt]);
#pragma unroll
    for (int s = 1; s < 16; s <<= 1) mx = fmaxf(mx, __shfl_xor(mx, s));
    float s0 = 0.f;
#pragma unroll
    for (int nt = 0; nt < 6; ++nt)
      s0 += __builtin_amdgcn_exp2f(1.442695040888963f * (v[nt] - mx));
#pragma unroll
    for (int s = 1; s < 16; s <<= 1) s0 += __shfl_xor(s0, s);
    float lg = __builtin_amdgcn_logf(s0) * 0.6931471805599453f + mx;
#pragma unroll
    for (int nt = 0; nt < 6; ++nt)
      out[(size_t)gm * LBL_ + nt * 16 + l15] = v[nt] - lg;
  }
}

extern "C" void kernel_launch(void* const* d_in, const int* in_sizes, int n_in,
                              void* d_out, int out_size, void* d_ws, size_t ws_size,
                              hipStream_t stream) {
  const float* enc = (const float*)d_in[0];
  const float* ptab = (const float*)d_in[1];
  const float* Wih = (const float*)d_in[2];
  const float* bih = (const float*)d_in[3];
  const float* Whh = (const float*)d_in[4];
  const float* bhh = (const float*)d_in[5];
  const float* combW = (const float*)d_in[6];
  const float* combb = (const float*)d_in[7];
  const float* linW = (const float*)d_in[8];
  const int* pid = (const int*)d_in[9];
  const int* sidx = (const int*)d_in[10];

  char* ws = (char*)d_ws;
  size_t off = 0;
  auto alloc = [&](size_t bytes) {
    void* p = ws + off;
    off += (bytes + 255) & ~(size_t)255;
    return p;
  };
  float* P = (float*)alloc((size_t)B_ * T_ * D2_ * 4);  // -> aliased by G
  u16* Xb = (u16*)alloc((size_t)T_ * B_ * KX_ * 2);     // -> aliased by H
  u16* Z = (u16*)alloc((size_t)T_ * B_ * HD_ * 2);      // S (2MB) lives here first
  u16* wc = (u16*)alloc(256 * KX_ * 2);
  u16* wih = (u16*)alloc(G4_ * HD_ * 2);
  u32* w4 = (u32*)alloc(G4_ * HD_ / 2);  // fp4 nibbles: 1024 x 128 B
  u16* wlin = (u16*)alloc(LPAD_ * KO_ * 2);
  float* biasg = (float*)alloc(G4_ * 4);
  u16* G = (u16*)P;
  u16* Hs = (u16*)Xb;
  float* S = (float*)Z;  // 1024*512 f32 = 2MB, dead before Z is written
  float* out = (float*)d_out;

  // threads: 163840(wc) + 262144(wih) + 32768(w4) + 98304(wlin) + 1024(biasg)
  k_prep<<<2180, 256, 0, stream>>>(combW, Wih, bih, Whh, bhh, linW, wc, wih, w4,
                                   wlin, biasg);
  k_psum<<<B_ * 16, 512, 0, stream>>>(enc, S);
  k_pwrite<<<B_ * 16, 512, 0, stream>>>(enc, S, P);
  k_xbuild<<<T_ * B_ / 4, 320, 0, stream>>>(P, ptab, pid, sidx, Xb);
  dim3 g3(512, 2);
  k_gemm<0><<<g3, 256, 0, stream>>>(Xb, wc, combb, Z);
  dim3 g4(512, 8);
  k_gemm<1><<<g4, 256, 0, stream>>>(Z, wih, biasg, G);
  k_seq<<<B_, 512, 0, stream>>>(G, w4, Hs);
  k_out<<<1024, 256, 0, stream>>>(Hs, enc, wlin, out);
}

// Round 10
// 904.671 us; speedup vs baseline: 5.7271x; 1.0016x over previous
//
#include <hip/hip_runtime.h>

typedef unsigned short u16;
typedef unsigned int u32;
typedef unsigned long long u64;
typedef __attribute__((ext_vector_type(8))) short short8;
typedef __attribute__((ext_vector_type(4))) float f32x4;
typedef __attribute__((ext_vector_type(8))) int i32x8;

#define B_ 64
#define T_ 1024
#define D2_ 512
#define HD_ 256
#define G4_ 1024
#define PD_ 100
#define KX_ 640
#define KO_ 768
#define LBL_ 96
#define LPAD_ 128
// e8m0 scale bytes (opsel=0 -> byte 0): A stored = h*4 -> 2^-2 (125);
// B stored = w*8 -> 2^-3 (124)
#define SCA 125
#define SCB 124

__device__ __forceinline__ float bf2f(u16 u) {
  u32 v = ((u32)u) << 16;
  return __builtin_bit_cast(float, v);
}
__device__ __forceinline__ u16 f2bf(float f) {
  u32 u = __builtin_bit_cast(u32, f);
  u32 r = (u + 0x7fffu + ((u >> 16) & 1u)) >> 16;
  return (u16)r;
}
__device__ __forceinline__ u32 pk2(float a, float b) {
  return (u32)f2bf(a) | ((u32)f2bf(b) << 16);
}
__device__ __forceinline__ float sgm(float x) {
  return __builtin_amdgcn_rcpf(1.f + __builtin_amdgcn_exp2f(-1.442695040888963f * x));
}
__device__ __forceinline__ float thh(float x) {
  return fmaf(-2.f,
              __builtin_amdgcn_rcpf(1.f + __builtin_amdgcn_exp2f(2.885390081777927f * x)),
              1.f);
}
// fp4 e2m1 encode of pre-scaled y (values {0,.5,1,1.5,2,3,4,6}), round-nearest
__device__ __forceinline__ u32 enc4(float y) {
  float a = fabsf(y);
  u32 c = 0;
  c = a >= 0.25f ? 1u : c;
  c = a >= 0.75f ? 2u : c;
  c = a >= 1.25f ? 3u : c;
  c = a >= 1.75f ? 4u : c;
  c = a >= 2.5f ? 5u : c;
  c = a >= 3.5f ? 6u : c;
  c = a >= 5.0f ? 7u : c;
  return c | ((__builtin_bit_cast(u32, y) >> 28) & 8u);
}

// ---------------- K0: weight prep ----------------
// wc: comb_W bf16 [256][640] padded; wih: W_ih bf16; w4: W_hh fp4 e2m1
// nibbles [1024][128B] (w*8, scale 2^-3); wlin: lin_W bf16 [128][768];
// biasg = b_ih + b_hh
__global__ __launch_bounds__(256) void k_prep(
    const float* combW, const float* Wih, const float* bih, const float* Whh,
    const float* bhh, const float* linW, u16* wc, u16* wih, u32* w4, u16* wlin,
    float* biasg) {
  int idx = blockIdx.x * 256 + threadIdx.x;
  if (idx < 256 * KX_) {
    int r = idx / KX_, c = idx % KX_;
    wc[idx] = f2bf(c < 612 ? combW[r * 612 + c] : 0.f);
    return;
  }
  idx -= 256 * KX_;
  if (idx < G4_ * HD_) { wih[idx] = f2bf(Wih[idx]); return; }
  idx -= G4_ * HD_;
  if (idx < G4_ * HD_ / 8) {  // 8 weights -> 1 u32 of nibbles (elem k at nibble k)
    int n = idx >> 5, c0 = (idx & 31) * 8;
    const float* wr = Whh + n * 256 + c0;
    u32 word = 0;
#pragma unroll
    for (int i = 0; i < 4; ++i) {
      u32 byte = enc4(wr[2 * i] * 8.f) | (enc4(wr[2 * i + 1] * 8.f) << 4);
      word |= byte << (8 * i);
    }
    w4[n * 32 + (c0 >> 3)] = word;
    return;
  }
  idx -= G4_ * HD_ / 8;
  if (idx < LPAD_ * KO_) {
    int r = idx / KO_;
    wlin[idx] = f2bf(r < LBL_ ? linW[idx] : 0.f);
    return;
  }
  idx -= LPAD_ * KO_;
  if (idx < G4_) biasg[idx] = bih[idx] + bhh[idx];
}

// ---------------- K1a: chunk sums S[b*16+c][d] = sum_{j<64} enc[b][c*64+j][d]
__global__ __launch_bounds__(512) void k_psum(const float* enc, float* S) {
  const int bc = blockIdx.x;  // b*16 + c
  const int d = threadIdx.x;
  const int b = bc >> 4, c = bc & 15;
  const float* e = enc + (((size_t)b * T_) + c * 64) * D2_ + d;
  float s = 0.f;
#pragma unroll 8
  for (int j = 0; j < 64; ++j) s += e[(size_t)j * D2_];
  S[(size_t)bc * D2_ + d] = s;
}

// ---------------- K1b: P[b][c*64+j][d] = chunk_offset + local exclusive scan
__global__ __launch_bounds__(512) void k_pwrite(const float* enc, const float* S,
                                                float* P) {
  const int bc = blockIdx.x;
  const int d = threadIdx.x;
  const int b = bc >> 4, c = bc & 15;
  float off = 0.f;
  for (int c2 = 0; c2 < c; ++c2) off += S[((size_t)(b * 16 + c2)) * D2_ + d];
  const float* e = enc + (((size_t)b * T_) + c * 64) * D2_ + d;
  float* p = P + (((size_t)b * T_) + c * 64) * D2_ + d;
#pragma unroll 4
  for (int j = 0; j < 64; ++j) {
    p[(size_t)j * D2_] = off;
    off += e[(size_t)j * D2_];
  }
}

// ---------------- K2: X rows [pe(100) | avg(512) | pad(28)] bf16 -------------
// 320 threads = 4 rows x 80 chunk-threads; each thread packs 8 elems (uint4).
__global__ __launch_bounds__(320) void k_xbuild(const float* P, const float* ptab,
                                                const int* pid, const int* sidx,
                                                u16* X) {
  const int tid = threadIdx.x;
  const int row = tid / 80;
  const int ir = tid - row * 80;
  const int m = blockIdx.x * 4 + row;  // m = t*64 + b
  const int t = m >> 6, b = m & 63;
  int pp = 0, ps = 0;
  if (t > 0) {
    pp = pid[(t - 1) * B_ + b];
    ps = sidx[(t - 1) * B_ + b];
  }
  bool valid = (ps >= 0) && (t > 0);
  int start = min(ps, t - 1);
  start = max(start, 0);
  start = min(start, T_ - 1);
  float invlen = 1.f / (float)max(t - start, 1);
  const float* Pt = P + ((size_t)b * T_ + t) * D2_;
  const float* Ps = P + ((size_t)b * T_ + start) * D2_;
  const int k0 = ir * 8;
  uint4 o;
  if (k0 >= 104 && k0 + 8 <= 612) {  // pure avg zone, 16B-aligned float4s
    if (valid) {
      int d = k0 - 100;
      float4 t0 = *(const float4*)(Pt + d), t1 = *(const float4*)(Pt + d + 4);
      float4 s0 = *(const float4*)(Ps + d), s1 = *(const float4*)(Ps + d + 4);
      o.x = pk2((t0.x - s0.x) * invlen, (t0.y - s0.y) * invlen);
      o.y = pk2((t0.z - s0.z) * invlen, (t0.w - s0.w) * invlen);
      o.z = pk2((t1.x - s1.x) * invlen, (t1.y - s1.y) * invlen);
      o.w = pk2((t1.z - s1.z) * invlen, (t1.w - s1.w) * invlen);
    } else {
      o = (uint4){0, 0, 0, 0};
    }
  } else if (k0 + 8 <= 100) {  // pure pos-table zone
    const float* pr = ptab + pp * PD_ + k0;
    o.x = pk2(pr[0], pr[1]);
    o.y = pk2(pr[2], pr[3]);
    o.z = pk2(pr[4], pr[5]);
    o.w = pk2(pr[6], pr[7]);
  } else if (k0 >= 616) {
    o = (uint4){0, 0, 0, 0};
  } else {  // mixed boundary chunks (ir == 12 or 76)
    u32 ow[4];
#pragma unroll
    for (int j2 = 0; j2 < 4; ++j2) {
      float v[2];
#pragma unroll
      for (int jj = 0; jj < 2; ++jj) {
        int k = k0 + j2 * 2 + jj;
        float x;
        if (k < PD_) x = ptab[pp * PD_ + k];
        else if (k < 612) x = valid ? (Pt[k - PD_] - Ps[k - PD_]) * invlen : 0.f;
        else x = 0.f;
        v[jj] = x;
      }
      ow[j2] = pk2(v[0], v[1]);
    }
    o = (uint4){ow[0], ow[1], ow[2], ow[3]};
  }
  *(uint4*)(X + (size_t)m * KX_ + k0) = o;
}

// ---------------- 128x128-tile bf16 MFMA GEMM: out = A @ Bw^T ----------------
// MODE 0: Z = tanh(X@Wc^T + comb_b), zero rows m<64, bf16 out, N=256, K=640
// MODE 1: G = Z@Wih^T + biasg -> layout G[m][cell*4+gate], N=1024, K=256
template <int MODE>
__global__ __launch_bounds__(256, 2) void k_gemm(const u16* A, const u16* Bw,
                                                 const float* bias, u16* outb) {
  constexpr int K = (MODE == 0) ? KX_ : HD_;
  constexpr int NOUT = (MODE == 0) ? 256 : 1024;
  __shared__ u16 As[128][40];
  __shared__ u16 Bs[128][40];
  const int m0 = blockIdx.x * 128, n0 = blockIdx.y * 128;
  const int tid = threadIdx.x;
  const int w = tid >> 6, l = tid & 63;
  const int wr = w >> 1, wc = w & 1;
  const int l15 = l & 15, lh = l >> 4;
  const int srow = tid >> 2, sc8 = (tid & 3) * 8;
  int brow0, brow1;
  if constexpr (MODE == 1) {
    int j0 = n0 + srow, j1 = n0 + srow + 64;
    brow0 = (j0 & 3) * 256 + (j0 >> 2);
    brow1 = (j1 & 3) * 256 + (j1 >> 2);
  } else {
    brow0 = n0 + srow;
    brow1 = n0 + srow + 64;
  }
  f32x4 acc[4][4] = {};
  for (int k0 = 0; k0 < K; k0 += 32) {
    uint4 a0 = *(const uint4*)(A + (size_t)(m0 + srow) * K + k0 + sc8);
    uint4 a1 = *(const uint4*)(A + (size_t)(m0 + srow + 64) * K + k0 + sc8);
    uint4 b0 = *(const uint4*)(Bw + (size_t)brow0 * K + k0 + sc8);
    uint4 b1 = *(const uint4*)(Bw + (size_t)brow1 * K + k0 + sc8);
    __syncthreads();  // previous iter's LDS reads complete
    *(uint4*)&As[srow][sc8] = a0;
    *(uint4*)&As[srow + 64][sc8] = a1;
    *(uint4*)&Bs[srow][sc8] = b0;
    *(uint4*)&Bs[srow + 64][sc8] = b1;
    __syncthreads();
    short8 af[4], bf[4];
#pragma unroll
    for (int i = 0; i < 4; ++i) {
      af[i] = *(const short8*)&As[wr * 64 + i * 16 + l15][lh * 8];
      bf[i] = *(const short8*)&Bs[wc * 64 + i * 16 + l15][lh * 8];
    }
#pragma unroll
    for (int mi = 0; mi < 4; ++mi)
#pragma unroll
      for (int ni = 0; ni < 4; ++ni)
        acc[mi][ni] =
            __builtin_amdgcn_mfma_f32_16x16x32_bf16(af[mi], bf[ni], acc[mi][ni], 0, 0, 0);
  }
#pragma unroll
  for (int mi = 0; mi < 4; ++mi)
#pragma unroll
    for (int ni = 0; ni < 4; ++ni)
#pragma unroll
      for (int r = 0; r < 4; ++r) {
        int gm = m0 + wr * 64 + mi * 16 + lh * 4 + r;
        int gn = n0 + wc * 64 + ni * 16 + l15;
        float v = acc[mi][ni][r];
        if constexpr (MODE == 0) {
          v = tanhf(v + bias[gn]);
          if (gm < 64) v = 0.f;  // t == 0 rows
          outb[(size_t)gm * NOUT + gn] = f2bf(v);
        } else {
          v += bias[(gn & 3) * 256 + (gn >> 2)];
          outb[(size_t)gm * NOUT + gn] = f2bf(v);
        }
      }
}

// ---------------- K5: sequential LSTM via MX fp4 MFMA (K=128, 2x rate) -------
// 8 waves. Wave w owns cells [w*32, w*32+32). B-frags held as PERSISTENT
// padded i32x8 (fp4 data in low 4 regs, zeros high) = 128 regs, parked in
// the unified VGPR/AGPR file where MFMA reads them for free — no per-step
// operand rebuild (round-9's VALU bottleneck). acc re-zeroed every step.
__global__ __launch_bounds__(512, 2) void k_seq(const u16* G, const u32* w4,
                                                u16* Hout) {
  __shared__ __align__(16) unsigned char hq[2][128];
  const int b = blockIdx.x;
  const int tid = threadIdx.x;
  const int w = tid >> 6, l = tid & 63;
  const int c16 = l & 15, quad = l >> 4;
  const unsigned char* w4b = (const unsigned char*)w4;
  i32x8 Bf[2][4][2];
#pragma unroll
  for (int ct = 0; ct < 2; ++ct)
#pragma unroll
    for (int g = 0; g < 4; ++g) {
      int n = g * 256 + w * 32 + ct * 16 + c16;
#pragma unroll
      for (int kb = 0; kb < 2; ++kb) {
        uint4 d = *(const uint4*)(w4b + (size_t)n * 128 + kb * 64 + quad * 16);
        Bf[ct][g][kb] =
            (i32x8){(int)d.x, (int)d.y, (int)d.z, (int)d.w, 0, 0, 0, 0};
      }
    }
  if (tid < 128) hq[0][tid] = 0;
  const int myct = quad >> 1;
  const int mycell = w * 32 + myct * 16 + c16;
  const u16* gptr = G + (size_t)b * 1024 + mycell * 4;
  u64 gq = *(const u64*)gptr;
  float cc = 0.f;
  int cur = 0;
  __syncthreads();
  for (int t = 0; t < T_; ++t) {
    int tn = (t + 1 < T_) ? t + 1 : t;
    u64 ngq = *(const u64*)(gptr + (size_t)tn * 65536);
    uint4 a0 = *(const uint4*)&hq[cur][quad * 16];       // kb=0: k 0..127
    uint4 a1 = *(const uint4*)&hq[cur][64 + quad * 16];  // kb=1: k 128..255
    i32x8 A0 = (i32x8){(int)a0.x, (int)a0.y, (int)a0.z, (int)a0.w, 0, 0, 0, 0};
    i32x8 A1 = (i32x8){(int)a1.x, (int)a1.y, (int)a1.z, (int)a1.w, 0, 0, 0, 0};
    f32x4 acc[2][4];
#pragma unroll
    for (int ct = 0; ct < 2; ++ct)
#pragma unroll
      for (int g = 0; g < 4; ++g) {
        f32x4 z4 = (f32x4){0.f, 0.f, 0.f, 0.f};
        z4 = __builtin_amdgcn_mfma_scale_f32_16x16x128_f8f6f4(
            A0, Bf[ct][g][0], z4, 4, 4, 0, SCA, 0, SCB);
        z4 = __builtin_amdgcn_mfma_scale_f32_16x16x128_f8f6f4(
            A1, Bf[ct][g][1], z4, 4, 4, 0, SCA, 0, SCB);
        acc[ct][g] = z4;
      }
    bool hi = (myct != 0);
    float vi = (hi ? acc[1][0][0] : acc[0][0][0]) + bf2f((u16)gq);
    float vf = (hi ? acc[1][1][0] : acc[0][1][0]) + bf2f((u16)(gq >> 16));
    float vg = (hi ? acc[1][2][0] : acc[0][2][0]) + bf2f((u16)(gq >> 32));
    float vo = (hi ? acc[1][3][0] : acc[0][3][0]) + bf2f((u16)(gq >> 48));
    cc = sgm(vf) * cc + sgm(vi) * thh(vg);
    float h = sgm(vo) * thh(cc);
    u32 nib = enc4(h * 4.f);                  // h scale 2^-2
    u32 nib2 = (u32)__shfl_xor((int)nib, 1);  // neighbor cell's nibble
    if ((quad & 1) == 0) {
      if ((c16 & 1) == 0)
        hq[cur ^ 1][mycell >> 1] = (unsigned char)(nib | (nib2 << 4));
      Hout[((size_t)b * 1024 + t) * 256 + mycell] = f2bf(h);
    }
    gq = ngq;
    cur ^= 1;
    __syncthreads();
  }
}

// ---------------- K6: fused output GEMM + log-softmax ------------------------
__global__ __launch_bounds__(256) void k_out(const u16* Hs, const float* enc,
                                             const u16* wlin, float* out) {
  __shared__ u16 As[64][40];
  __shared__ u16 Bs[128][40];
  const int m0 = blockIdx.x * 64;
  const int tid = threadIdx.x;
  const int srow = tid >> 2, sc8 = (tid & 3) * 8;
  const int brow = tid >> 1, bc16 = (tid & 1) * 16;
  const int w = tid >> 6, l = tid & 63;
  const int l15 = l & 15, lh = l >> 4;
  f32x4 acc[8] = {};
  for (int k0 = 0; k0 < KO_; k0 += 32) {
    int k = k0 + sc8;
    uint4 av;
    if (k < 256) {
      av = *(const uint4*)(Hs + (size_t)(m0 + srow) * 256 + k);
    } else {
      const float* src = enc + (size_t)(m0 + srow) * 512 + (k - 256);
      float4 f0 = *(const float4*)(src);
      float4 f1 = *(const float4*)(src + 4);
      av.x = pk2(f0.x, f0.y);
      av.y = pk2(f0.z, f0.w);
      av.z = pk2(f1.x, f1.y);
      av.w = pk2(f1.z, f1.w);
    }
    *(uint4*)&As[srow][sc8] = av;
    const u16* bsrc = wlin + (size_t)brow * KO_ + k0 + bc16;
    *(uint4*)&Bs[brow][bc16] = *(const uint4*)(bsrc);
    *(uint4*)&Bs[brow][bc16 + 8] = *(const uint4*)(bsrc + 8);
    __syncthreads();
    short8 a8 = *(const short8*)&As[16 * w + l15][lh * 8];
#pragma unroll
    for (int nt = 0; nt < 8; ++nt) {
      short8 b8 = *(const short8*)&Bs[nt * 16 + l15][lh * 8];
      acc[nt] = __builtin_amdgcn_mfma_f32_16x16x32_bf16(a8, b8, acc[nt], 0, 0, 0);
    }
    __syncthreads();
  }
#pragma unroll
  for (int r = 0; r < 4; ++r) {
    int gm = m0 + 16 * w + lh * 4 + r;
    float v[8];
#pragma unroll
    for (int nt = 0; nt < 8; ++nt) v[nt] = acc[nt][r];
    if ((gm & (T_ - 1)) == 0 && l15 == 1) v[0] = -1e10f;  // t==0, col==APP_ID
    float mx = v[0];
#pragma unroll
    for (int nt = 1; nt < 6; ++nt) mx = fmaxf(mx, v[nt]);
#pragma unroll
    for (int s = 1; s < 16; s <<= 1) mx = fmaxf(mx, __shfl_xor(mx, s));
    float s0 = 0.f;
#pragma unroll
    for (int nt = 0; nt < 6; ++nt)
      s0 += __builtin_amdgcn_exp2f(1.442695040888963f * (v[nt] - mx));
#pragma unroll
    for (int s = 1; s < 16; s <<= 1) s0 += __shfl_xor(s0, s);
    float lg = __builtin_amdgcn_logf(s0) * 0.6931471805599453f + mx;
#pragma unroll
    for (int nt = 0; nt < 6; ++nt)
      out[(size_t)gm * LBL_ + nt * 16 + l15] = v[nt] - lg;
  }
}

extern "C" void kernel_launch(void* const* d_in, const int* in_sizes, int n_in,
                              void* d_out, int out_size, void* d_ws, size_t ws_size,
                              hipStream_t stream) {
  const float* enc = (const float*)d_in[0];
  const float* ptab = (const float*)d_in[1];
  const float* Wih = (const float*)d_in[2];
  const float* bih = (const float*)d_in[3];
  const float* Whh = (const float*)d_in[4];
  const float* bhh = (const float*)d_in[5];
  const float* combW = (const float*)d_in[6];
  const float* combb = (const float*)d_in[7];
  const float* linW = (const float*)d_in[8];
  const int* pid = (const int*)d_in[9];
  const int* sidx = (const int*)d_in[10];

  char* ws = (char*)d_ws;
  size_t off = 0;
  auto alloc = [&](size_t bytes) {
    void* p = ws + off;
    off += (bytes + 255) & ~(size_t)255;
    return p;
  };
  float* P = (float*)alloc((size_t)B_ * T_ * D2_ * 4);  // -> aliased by G
  u16* Xb = (u16*)alloc((size_t)T_ * B_ * KX_ * 2);     // -> aliased by H
  u16* Z = (u16*)alloc((size_t)T_ * B_ * HD_ * 2);      // S (2MB) lives here first
  u16* wc = (u16*)alloc(256 * KX_ * 2);
  u16* wih = (u16*)alloc(G4_ * HD_ * 2);
  u32* w4 = (u32*)alloc(G4_ * HD_ / 2);  // fp4 nibbles: 1024 x 128 B
  u16* wlin = (u16*)alloc(LPAD_ * KO_ * 2);
  float* biasg = (float*)alloc(G4_ * 4);
  u16* G = (u16*)P;
  u16* Hs = (u16*)Xb;
  float* S = (float*)Z;  // 1024*512 f32 = 2MB, dead before Z is written
  float* out = (float*)d_out;

  // threads: 163840(wc) + 262144(wih) + 32768(w4) + 98304(wlin) + 1024(biasg)
  k_prep<<<2180, 256, 0, stream>>>(combW, Wih, bih, Whh, bhh, linW, wc, wih, w4,
                                   wlin, biasg);
  k_psum<<<B_ * 16, 512, 0, stream>>>(enc, S);
  k_pwrite<<<B_ * 16, 512, 0, stream>>>(enc, S, P);
  k_xbuild<<<T_ * B_ / 4, 320, 0, stream>>>(P, ptab, pid, sidx, Xb);
  dim3 g3(512, 2);
  k_gemm<0><<<g3, 256, 0, stream>>>(Xb, wc, combb, Z);
  dim3 g4(512, 8);
  k_gemm<1><<<g4, 256, 0, stream>>>(Z, wih, biasg, G);
  k_seq<<<B_, 512, 0, stream>>>(G, w4, Hs);
  k_out<<<1024, 256, 0, stream>>>(Hs, enc, wlin, out);
}